// Round 2
// baseline (8673.861 us; speedup 1.0000x reference)
//
#include <hip/hip_runtime.h>
#include <stdint.h>
#include <math.h>

typedef unsigned short ushort_t;
typedef __bf16 bf16x8 __attribute__((ext_vector_type(8)));
typedef unsigned short ushx8 __attribute__((ext_vector_type(8)));
typedef unsigned short ushx4 __attribute__((ext_vector_type(4)));
typedef float f32x4 __attribute__((ext_vector_type(4)));

#define DEV static __device__ __forceinline__

DEV float bf2f(ushort_t h) {
    union { unsigned u; float f; } v;
    v.u = ((unsigned)h) << 16;
    return v.f;
}
DEV ushort_t f2bf(float f) {
    union { float f; unsigned u; } v;
    v.f = f;
    unsigned r = v.u + 0x7fffu + ((v.u >> 16) & 1u);
    return (ushort_t)(r >> 16);
}
// runtime-dtype input read (flat element index): flag -> fp32, else bf16 bits
DEV float ldin(const void* p, size_t i, int isf32) {
    return isf32 ? ((const float*)p)[i] : bf2f(((const ushort_t*)p)[i]);
}

// ---------------- dtype detector: writes 1 if inputs are fp32 ----------------
__global__ __launch_bounds__(256) void detect_kernel(const ushort_t* __restrict__ x,
                                                     int* __restrict__ flag) {
    __shared__ int bad;
    if (threadIdx.x == 0) bad = 0;
    __syncthreads();
    int b = 0;
#pragma unroll
    for (int i = 0; i < 8; ++i) {
        float v = fabsf(bf2f(x[threadIdx.x * 8 + i]));
        if (!(v <= 16384.f)) b = 1;  // catches huge exponents AND NaN
    }
    if (b) atomicOr(&bad, 1);
    __syncthreads();
    if (threadIdx.x == 0) *flag = bad;
}

// ---------------- PE add: X = x + pos_encoding ----------------
__global__ __launch_bounds__(256) void pe_kernel(const void* __restrict__ x,
                                                 float* __restrict__ X,
                                                 const int* __restrict__ flag) {
    const int isf32 = *flag;
    int i = blockIdx.x * 256 + threadIdx.x;
    int d = i & 511;
    int s = (i >> 9) & 1023;
    float freq = expf((float)(d & ~1) * (-9.210340371976184f / 512.f));
    float ang = (float)s * freq;
    float pe = (d & 1) ? cosf(ang) : sinf(ang);
    X[i] = ldin(x, i, isf32) + pe;
}

// ---------------- MFMA bf16 GEMM: C = A(MxK) @ W(KxN) + bias ----------------
// A: fp32 or bf16 (compile-time). W,bias: runtime dtype + element offsets.
template <typename AT, typename CT, bool RELU>
__global__ __launch_bounds__(256) void gemm_kernel(const AT* __restrict__ A,
                                                   const void* __restrict__ W, size_t wOff,
                                                   const void* __restrict__ bias, size_t bOff,
                                                   CT* __restrict__ C,
                                                   int M, int K, int N,
                                                   const int* __restrict__ flag) {
    const int isf32 = *flag;
    constexpr int LDT = 40;  // LDS row stride (bf16 units): 32 + 8 pad
    __shared__ ushort_t As[128 * LDT];
    __shared__ ushort_t Bs[128 * LDT];
    const int tid = threadIdx.x;
    const int bm = blockIdx.y * 128;
    const int bn = blockIdx.x * 128;
    const int wave = tid >> 6, lane = tid & 63;
    const int wm = (wave >> 1) * 64, wn = (wave & 1) * 64;

    f32x4 acc[4][4];
#pragma unroll
    for (int i = 0; i < 4; ++i)
#pragma unroll
        for (int j = 0; j < 4; ++j) acc[i][j] = (f32x4){0.f, 0.f, 0.f, 0.f};

    const int ar = tid >> 1;          // 0..127 : A row in tile
    const int ak = (tid & 1) * 16;    // 0/16   : A k-offset
    const int bnn = tid & 127;        // 0..127 : B col in tile
    const int bk = (tid >> 7) * 16;   // 0/16   : B k-offset

    const int fm = lane & 15;
    const int fk = (lane >> 4) * 8;

    for (int k0 = 0; k0 < K; k0 += 32) {
        // --- stage A tile ---
        if constexpr (sizeof(AT) == 4) {
            const float* ap = (const float*)A + (size_t)(bm + ar) * K + k0 + ak;
            ushort_t tmp[16];
#pragma unroll
            for (int i = 0; i < 16; i += 4) {
                float4 f = *(const float4*)(ap + i);
                tmp[i + 0] = f2bf(f.x);
                tmp[i + 1] = f2bf(f.y);
                tmp[i + 2] = f2bf(f.z);
                tmp[i + 3] = f2bf(f.w);
            }
#pragma unroll
            for (int i = 0; i < 16; i += 4)
                *(ushx4*)&As[ar * LDT + ak + i] = *(ushx4*)&tmp[i];
        } else {
            const ushort_t* ap = (const ushort_t*)A + (size_t)(bm + ar) * K + k0 + ak;
            *(ushx8*)&As[ar * LDT + ak] = *(const ushx8*)ap;
            *(ushx8*)&As[ar * LDT + ak + 8] = *(const ushx8*)(ap + 8);
        }
        // --- stage B tile transposed: Bs[n][k] ---
        {
            const size_t we = wOff + (size_t)(k0 + bk) * N + bn + bnn;
            ushort_t tmp[16];
            if (isf32) {
                const float* wp = (const float*)W + we;
#pragma unroll
                for (int i = 0; i < 16; ++i) tmp[i] = f2bf(wp[(size_t)i * N]);
            } else {
                const ushort_t* wp = (const ushort_t*)W + we;
#pragma unroll
                for (int i = 0; i < 16; ++i) tmp[i] = wp[(size_t)i * N];
            }
#pragma unroll
            for (int i = 0; i < 16; i += 8)
                *(ushx8*)&Bs[bnn * LDT + bk + i] = *(ushx8*)&tmp[i];
        }
        __syncthreads();
        bf16x8 af[4], bfr[4];
#pragma unroll
        for (int i = 0; i < 4; ++i)
            af[i] = __builtin_bit_cast(bf16x8, *(const ushx8*)&As[(wm + i * 16 + fm) * LDT + fk]);
#pragma unroll
        for (int j = 0; j < 4; ++j)
            bfr[j] = __builtin_bit_cast(bf16x8, *(const ushx8*)&Bs[(wn + j * 16 + fm) * LDT + fk]);
#pragma unroll
        for (int i = 0; i < 4; ++i)
#pragma unroll
            for (int j = 0; j < 4; ++j)
                acc[i][j] = __builtin_amdgcn_mfma_f32_16x16x32_bf16(af[i], bfr[j], acc[i][j], 0, 0, 0);
        __syncthreads();
    }
    // --- epilogue: C/D layout col=lane&15, row=(lane>>4)*4+reg ---
    const int cn = lane & 15;
    const int rq = (lane >> 4) * 4;
#pragma unroll
    for (int j = 0; j < 4; ++j) {
        const int n = bn + wn + j * 16 + cn;
        const float bv = ldin(bias, bOff + n, isf32);
#pragma unroll
        for (int i = 0; i < 4; ++i) {
#pragma unroll
            for (int r = 0; r < 4; ++r) {
                const int m = bm + wm + i * 16 + rq + r;
                float v = acc[i][j][r] + bv;
                if constexpr (RELU) v = fmaxf(v, 0.f);
                if constexpr (sizeof(CT) == 4)
                    ((float*)C)[(size_t)m * N + n] = v;
                else
                    ((ushort_t*)C)[(size_t)m * N + n] = f2bf(v);
            }
        }
    }
}

// ---------------- Attention: per (b, h, 8-query strip) ----------------
__global__ __launch_bounds__(256) void attn_kernel(const float* __restrict__ Q,
                                                   const float* __restrict__ Kb,
                                                   const float* __restrict__ V,
                                                   const int* __restrict__ lens,
                                                   float* __restrict__ O) {
    __shared__ float qs[8][64];
    __shared__ float sc[8][1024];  // 32 KB
    const int qt = blockIdx.x, h = blockIdx.y, b = blockIdx.z;
    const int tid = threadIdx.x;
    const int len = lens[b];
    const size_t base = ((size_t)b * 1024) * 512 + h * 64;
    for (int i = tid; i < 8 * 64; i += 256) {
        int qi = i >> 6, d = i & 63;
        qs[qi][d] = Q[base + (size_t)(qt * 8 + qi) * 512 + d] * 0.125f;
    }
    __syncthreads();
    for (int it = 0; it < 32; ++it) {
        int idx = it * 256 + tid;
        int qi = idx >> 10, ki = idx & 1023;
        float s = -1e30f;
        if (ki < len) {
            const float4* kr = (const float4*)(Kb + base + (size_t)ki * 512);
            const float4* qr = (const float4*)qs[qi];
            float a0 = 0.f;
#pragma unroll
            for (int d4 = 0; d4 < 16; ++d4) {
                float4 kv = kr[d4];
                float4 qv = qr[d4];
                a0 += kv.x * qv.x + kv.y * qv.y + kv.z * qv.z + kv.w * qv.w;
            }
            s = a0;
        }
        sc[qi][ki] = s;
    }
    __syncthreads();
    const int wave = tid >> 6, lane = tid & 63;
    for (int r = wave * 2; r < wave * 2 + 2; ++r) {
        float m = -1e30f;
        for (int i = lane; i < 1024; i += 64) m = fmaxf(m, sc[r][i]);
#pragma unroll
        for (int o = 32; o; o >>= 1) m = fmaxf(m, __shfl_xor(m, o));
        float sum = 0.f;
        for (int i = lane; i < 1024; i += 64) {
            float e = __expf(sc[r][i] - m);
            sc[r][i] = e;
            sum += e;
        }
#pragma unroll
        for (int o = 32; o; o >>= 1) sum += __shfl_xor(sum, o);
        float inv = 1.f / sum;
        for (int i = lane; i < 1024; i += 64) sc[r][i] *= inv;
    }
    __syncthreads();
    const int qi = tid >> 5;
    const int dg = (tid & 31) * 2;
    const float2* vp = (const float2*)(V + base + dg);
    float2 a2 = {0.f, 0.f};
    for (int ki = 0; ki < len; ++ki) {
        float w = sc[qi][ki];
        float2 v2 = vp[(size_t)ki * 256];
        a2.x += w * v2.x;
        a2.y += w * v2.y;
    }
    *(float2*)&O[base + (size_t)(qt * 8 + qi) * 512 + dg] = a2;
}

// ---------------- Residual + LayerNorm ----------------
__global__ __launch_bounds__(256) void ln_kernel(const float* __restrict__ A,
                                                 const float* __restrict__ B,
                                                 const void* __restrict__ g,
                                                 const void* __restrict__ be, size_t pOff,
                                                 float* __restrict__ out,
                                                 const int* __restrict__ flag) {
    const int isf32 = *flag;
    __shared__ float red[8];
    const int row = blockIdx.x, tid = threadIdx.x;
    const int wave = tid >> 6, lane = tid & 63;
    const size_t off = (size_t)row * 512;
    float v0 = A[off + tid] + B[off + tid];
    float v1 = A[off + tid + 256] + B[off + tid + 256];
    float s = v0 + v1;
#pragma unroll
    for (int o = 32; o; o >>= 1) s += __shfl_xor(s, o);
    if (lane == 0) red[wave] = s;
    __syncthreads();
    const float mean = (red[0] + red[1] + red[2] + red[3]) * (1.f / 512.f);
    const float d0 = v0 - mean, d1 = v1 - mean;
    float ss = d0 * d0 + d1 * d1;
#pragma unroll
    for (int o = 32; o; o >>= 1) ss += __shfl_xor(ss, o);
    if (lane == 0) red[4 + wave] = ss;
    __syncthreads();
    const float var = (red[4] + red[5] + red[6] + red[7]) * (1.f / 511.f);
    const float inv = 1.f / (sqrtf(var) + 1e-6f);
    out[off + tid] = ldin(g, pOff + tid, isf32) * d0 * inv + ldin(be, pOff + tid, isf32);
    out[off + tid + 256] = ldin(g, pOff + tid + 256, isf32) * d1 * inv + ldin(be, pOff + tid + 256, isf32);
}

// ---------------- final fp32 -> output dtype ----------------
__global__ __launch_bounds__(256) void out_kernel(const float* __restrict__ X,
                                                  void* __restrict__ out,
                                                  const int* __restrict__ flag) {
    const int isf32 = *flag;
    int i = blockIdx.x * 256 + threadIdx.x;
    if (isf32)
        ((float*)out)[i] = X[i];
    else
        ((ushort_t*)out)[i] = f2bf(X[i]);
}

extern "C" void kernel_launch(void* const* d_in, const int* in_sizes, int n_in,
                              void* d_out, int out_size, void* d_ws, size_t ws_size,
                              hipStream_t stream) {
    const void* x   = d_in[0];
    const int* lens = (const int*)d_in[1];
    const void* Wq  = d_in[2];
    const void* bq  = d_in[3];
    const void* Wk  = d_in[4];
    const void* bk  = d_in[5];
    const void* Wv  = d_in[6];
    const void* bv  = d_in[7];
    const void* Wo  = d_in[8];
    const void* bo  = d_in[9];
    const void* W1  = d_in[10];
    const void* b1  = d_in[11];
    const void* W2  = d_in[12];
    const void* b2  = d_in[13];
    const void* g1  = d_in[14];
    const void* be1 = d_in[15];
    const void* g2  = d_in[16];
    const void* be2 = d_in[17];

    const size_t NE = (size_t)8 * 1024 * 512;  // 4194304 activation elems
    int* flag = (int*)d_ws;
    float* A0 = (float*)((char*)d_ws + 256);  // X (current input)
    float* A1 = A0 + NE;                      // Q -> ATT
    float* A2 = A1 + NE;                      // K -> AO -> F2
    float* A3 = A2 + NE;                      // V -> Y
    ushort_t* F1 = (ushort_t*)((char*)d_ws + 256);  // 8192x2048 bf16, overlaps A0+A1

    dim3 blk(256);
    dim3 gD(512 / 128, 8192 / 128);   // (4, 64)
    dim3 gF(2048 / 128, 8192 / 128);  // (16, 64)

    detect_kernel<<<1, blk, 0, stream>>>((const ushort_t*)x, flag);
    pe_kernel<<<NE / 256, blk, 0, stream>>>(x, A0, flag);
    for (int l = 0; l < 4; ++l) {
        const size_t wD = (size_t)l * 512 * 512;   // dense weight elem offset
        const size_t wF = (size_t)l * 512 * 2048;  // ff weight elem offset
        const size_t bD = (size_t)l * 512;
        const size_t bF = (size_t)l * 2048;

        gemm_kernel<float, float, false><<<gD, blk, 0, stream>>>(A0, Wq, wD, bq, bD, A1, 8192, 512, 512, flag);
        gemm_kernel<float, float, false><<<gD, blk, 0, stream>>>(A0, Wk, wD, bk, bD, A2, 8192, 512, 512, flag);
        gemm_kernel<float, float, false><<<gD, blk, 0, stream>>>(A0, Wv, wD, bv, bD, A3, 8192, 512, 512, flag);
        attn_kernel<<<dim3(128, 8, 8), blk, 0, stream>>>(A1, A2, A3, lens, A1);
        gemm_kernel<float, float, false><<<gD, blk, 0, stream>>>(A1, Wo, wD, bo, bD, A2, 8192, 512, 512, flag);
        ln_kernel<<<8192, blk, 0, stream>>>(A0, A2, g1, be1, bD, A3, flag);
        gemm_kernel<float, ushort_t, true><<<gF, blk, 0, stream>>>(A3, W1, wF, b1, bF, F1, 8192, 512, 2048, flag);
        gemm_kernel<ushort_t, float, false><<<gD, blk, 0, stream>>>(F1, W2, wF, b2, bD, A2, 8192, 2048, 512, flag);
        ln_kernel<<<8192, blk, 0, stream>>>(A3, A2, g2, be2, bD, A0, flag);
    }
    out_kernel<<<NE / 256, blk, 0, stream>>>(A0, d_out, flag);
}

// Round 4
// 1345.542 us; speedup vs baseline: 6.4464x; 6.4464x over previous
//
#include <hip/hip_runtime.h>
#include <stdint.h>
#include <math.h>

typedef unsigned short ushort_t;
typedef __bf16 bf16x8 __attribute__((ext_vector_type(8)));
typedef unsigned short ushx8 __attribute__((ext_vector_type(8)));
typedef float f32x4 __attribute__((ext_vector_type(4)));

#define DEV static __device__ __forceinline__

DEV float bf2f(ushort_t h) {
    union { unsigned u; float f; } v;
    v.u = ((unsigned)h) << 16;
    return v.f;
}
DEV ushort_t f2bf(float f) {
    union { float f; unsigned u; } v;
    v.f = f;
    unsigned r = v.u + 0x7fffu + ((v.u >> 16) & 1u);
    return (ushort_t)(r >> 16);
}
// runtime-dtype input read (flat element index): flag -> fp32, else bf16 bits
DEV float ldin(const void* p, size_t i, int isf32) {
    return isf32 ? ((const float*)p)[i] : bf2f(((const ushort_t*)p)[i]);
}
DEV bf16x8 ldfrag(const ushort_t* p) {
    return __builtin_bit_cast(bf16x8, *(const ushx8*)p);
}

// ---------------- dtype detector: writes 1 if inputs are fp32 ----------------
__global__ __launch_bounds__(256) void detect_kernel(const ushort_t* __restrict__ x,
                                                     int* __restrict__ flag) {
    __shared__ int bad;
    if (threadIdx.x == 0) bad = 0;
    __syncthreads();
    int b = 0;
#pragma unroll
    for (int i = 0; i < 8; ++i) {
        float v = fabsf(bf2f(x[threadIdx.x * 8 + i]));
        if (!(v <= 16384.f)) b = 1;  // catches huge exponents AND NaN
    }
    if (b) atomicOr(&bad, 1);
    __syncthreads();
    if (threadIdx.x == 0) *flag = bad;
}

// ---------------- PE add: X(bf16) = x + pos_encoding ----------------
__global__ __launch_bounds__(256) void pe_kernel(const void* __restrict__ x,
                                                 ushort_t* __restrict__ X,
                                                 const int* __restrict__ flag) {
    const int isf32 = *flag;
    int i = blockIdx.x * 256 + threadIdx.x;
    int d = i & 511;
    int s = (i >> 9) & 1023;
    float freq = expf((float)(d & ~1) * (-9.210340371976184f / 512.f));
    float ang = (float)s * freq;
    float pe = (d & 1) ? cosf(ang) : sinf(ang);
    X[i] = f2bf(ldin(x, i, isf32) + pe);
}

// ---------------- MFMA bf16 GEMM: C = A(MxK,bf16) @ W(KxN) + bias ----------------
// CT: float (fp32 out) or ushort_t (bf16 out). Optional ReLU.
template <typename CT, bool RELU>
__global__ __launch_bounds__(256) void gemm_kernel(const ushort_t* __restrict__ A,
                                                   const void* __restrict__ W, size_t wOff,
                                                   const void* __restrict__ bias, size_t bOff,
                                                   CT* __restrict__ C,
                                                   int M, int K, int N,
                                                   const int* __restrict__ flag) {
    const int isf32 = *flag;
    constexpr int LDT = 40;  // 80 B/row: 16B-aligned, +8 pad
    __shared__ ushort_t As[128 * LDT];
    __shared__ ushort_t Bs[128 * LDT];
    const int tid = threadIdx.x;
    const int bm = blockIdx.y * 128;
    const int bn = blockIdx.x * 128;
    const int wave = tid >> 6, lane = tid & 63;
    const int wm = (wave >> 1) * 64, wn = (wave & 1) * 64;

    f32x4 acc[4][4];
#pragma unroll
    for (int i = 0; i < 4; ++i)
#pragma unroll
        for (int j = 0; j < 4; ++j) acc[i][j] = (f32x4){0.f, 0.f, 0.f, 0.f};

    const int ar = tid >> 1;          // 0..127 : A row in tile
    const int ak = (tid & 1) * 16;    // 0/16   : A k-offset
    const int bnn = tid & 127;        // 0..127 : B col in tile
    const int bk = (tid >> 7) * 16;   // 0/16   : B k-offset

    const int fm = lane & 15;
    const int fk = (lane >> 4) * 8;

    for (int k0 = 0; k0 < K; k0 += 32) {
        // --- stage A tile (bf16, vector copies) ---
        {
            const ushort_t* ap = A + (size_t)(bm + ar) * K + k0 + ak;
            *(ushx8*)&As[ar * LDT + ak] = *(const ushx8*)ap;
            *(ushx8*)&As[ar * LDT + ak + 8] = *(const ushx8*)(ap + 8);
        }
        // --- stage B tile transposed: Bs[n][k] ---
        {
            const size_t we = wOff + (size_t)(k0 + bk) * N + bn + bnn;
            ushort_t tmp[16];
            if (isf32) {
                const float* wp = (const float*)W + we;
#pragma unroll
                for (int i = 0; i < 16; ++i) tmp[i] = f2bf(wp[(size_t)i * N]);
            } else {
                const ushort_t* wp = (const ushort_t*)W + we;
#pragma unroll
                for (int i = 0; i < 16; ++i) tmp[i] = wp[(size_t)i * N];
            }
#pragma unroll
            for (int i = 0; i < 16; i += 8)
                *(ushx8*)&Bs[bnn * LDT + bk + i] = *(ushx8*)&tmp[i];
        }
        __syncthreads();
        bf16x8 af[4], bfr[4];
#pragma unroll
        for (int i = 0; i < 4; ++i)
            af[i] = ldfrag(&As[(wm + i * 16 + fm) * LDT + fk]);
#pragma unroll
        for (int j = 0; j < 4; ++j)
            bfr[j] = ldfrag(&Bs[(wn + j * 16 + fm) * LDT + fk]);
#pragma unroll
        for (int i = 0; i < 4; ++i)
#pragma unroll
            for (int j = 0; j < 4; ++j)
                acc[i][j] = __builtin_amdgcn_mfma_f32_16x16x32_bf16(af[i], bfr[j], acc[i][j], 0, 0, 0);
        __syncthreads();
    }
    // --- epilogue: C/D layout col=lane&15, row=(lane>>4)*4+reg ---
    const int cn = lane & 15;
    const int rq = (lane >> 4) * 4;
#pragma unroll
    for (int j = 0; j < 4; ++j) {
        const int n = bn + wn + j * 16 + cn;
        const float bv = ldin(bias, bOff + n, isf32);
#pragma unroll
        for (int i = 0; i < 4; ++i) {
#pragma unroll
            for (int r = 0; r < 4; ++r) {
                const int m = bm + wm + i * 16 + rq + r;
                float v = acc[i][j][r] + bv;
                if constexpr (RELU) v = fmaxf(v, 0.f);
                if constexpr (sizeof(CT) == 4)
                    ((float*)C)[(size_t)m * N + n] = v;
                else
                    ((ushort_t*)C)[(size_t)m * N + n] = f2bf(v);
            }
        }
    }
}

// ---------------- Flash attention (MFMA, bf16 I/O): block = (b,h,64-q tile) ----------------
// Q,K,V,O bf16 activations (b, s, h*64+d). O is a SEPARATE buffer (no aliasing).
__global__ __launch_bounds__(256) void fattn_kernel(const ushort_t* __restrict__ Q,
                                                    const ushort_t* __restrict__ Kb,
                                                    const ushort_t* __restrict__ V,
                                                    const int* __restrict__ lens,
                                                    ushort_t* __restrict__ O) {
    constexpr int LDT = 72;  // 144 B/row: 16B-aligned b128, 2-way bank alias only (free)
    __shared__ ushort_t Qs[64 * LDT];
    __shared__ ushort_t Ks[64 * LDT];
    __shared__ ushort_t Vs[64 * LDT];  // transposed: Vs[d][key]
    __shared__ ushort_t Ps[64 * LDT];  // wave-private 16-row strips
    const int qt = blockIdx.x, h = blockIdx.y, b = blockIdx.z;
    const int tid = threadIdx.x, w = tid >> 6, L = tid & 63;
    const int len = lens[b];
    const size_t hb = ((size_t)b * 1024) * 512 + (size_t)h * 64;
    const int fm = L & 15;            // frag row (A/B m/n)
    const int fk = (L >> 4) * 8;      // frag k offset
    const int cl = L & 15;            // C col
    const int rq = (L >> 4) * 4;      // C row base

    const int srow = tid >> 2;        // 0..63 staging row
    const int sc0 = (tid & 3) * 16;   // staging col base

    // stage Q tile (raw; 1/sqrt(64) applied post-MFMA in fp32)
    {
        const ushx8* qp = (const ushx8*)(Q + hb + (size_t)(qt * 64 + srow) * 512 + sc0);
        *(ushx8*)&Qs[srow * LDT + sc0] = qp[0];
        *(ushx8*)&Qs[srow * LDT + sc0 + 8] = qp[1];
    }

    float mrow[4], lrow[4];
    f32x4 oacc[4];
#pragma unroll
    for (int r = 0; r < 4; ++r) { mrow[r] = -1e30f; lrow[r] = 0.f; }
#pragma unroll
    for (int dt = 0; dt < 4; ++dt) oacc[dt] = (f32x4){0.f, 0.f, 0.f, 0.f};

    const int nkb = (len + 63) >> 6;
    for (int kb = 0; kb < nkb; ++kb) {
        __syncthreads();  // prior consumers done before re-staging Ks/Vs
        {
            const ushx8* kp = (const ushx8*)(Kb + hb + (size_t)(kb * 64 + srow) * 512 + sc0);
            const ushx8* vp = (const ushx8*)(V + hb + (size_t)(kb * 64 + srow) * 512 + sc0);
            *(ushx8*)&Ks[srow * LDT + sc0] = kp[0];
            *(ushx8*)&Ks[srow * LDT + sc0 + 8] = kp[1];
            ushx8 v0 = vp[0], v1 = vp[1];
#pragma unroll
            for (int i = 0; i < 8; ++i) Vs[(sc0 + i) * LDT + srow] = v0[i];
#pragma unroll
            for (int i = 0; i < 8; ++i) Vs[(sc0 + 8 + i) * LDT + srow] = v1[i];
        }
        __syncthreads();
        // --- S strip (16 q x 64 k) = Q strip @ K^T ---
        f32x4 sacc[4];
#pragma unroll
        for (int j = 0; j < 4; ++j) sacc[j] = (f32x4){0.f, 0.f, 0.f, 0.f};
#pragma unroll
        for (int st = 0; st < 2; ++st) {
            bf16x8 af = ldfrag(&Qs[(w * 16 + fm) * LDT + st * 32 + fk]);
#pragma unroll
            for (int j = 0; j < 4; ++j) {
                bf16x8 bf = ldfrag(&Ks[(j * 16 + fm) * LDT + st * 32 + fk]);
                sacc[j] = __builtin_amdgcn_mfma_f32_16x16x32_bf16(af, bf, sacc[j], 0, 0, 0);
            }
        }
        // --- scale + mask + online softmax (rows live in 16-lane col groups) ---
        const int colb = kb * 64;
        float nm[4] = {-1e30f, -1e30f, -1e30f, -1e30f};
#pragma unroll
        for (int j = 0; j < 4; ++j) {
            const bool mk = (colb + j * 16 + cl) >= len;
#pragma unroll
            for (int r = 0; r < 4; ++r) {
                float s = mk ? -1e30f : sacc[j][r] * 0.125f;
                sacc[j][r] = s;
                nm[r] = fmaxf(nm[r], s);
            }
        }
#pragma unroll
        for (int msk = 1; msk <= 8; msk <<= 1)
#pragma unroll
            for (int r = 0; r < 4; ++r) nm[r] = fmaxf(nm[r], __shfl_xor(nm[r], msk));
        float alpha[4], rs[4];
#pragma unroll
        for (int r = 0; r < 4; ++r) {
            float mn = fmaxf(mrow[r], nm[r]);
            alpha[r] = __expf(mrow[r] - mn);
            mrow[r] = mn;
            rs[r] = 0.f;
        }
#pragma unroll
        for (int j = 0; j < 4; ++j) {
            const bool mk = (colb + j * 16 + cl) >= len;
#pragma unroll
            for (int r = 0; r < 4; ++r) {
                float p = mk ? 0.f : __expf(sacc[j][r] - mrow[r]);
                sacc[j][r] = p;
                rs[r] += p;
            }
        }
#pragma unroll
        for (int msk = 1; msk <= 8; msk <<= 1)
#pragma unroll
            for (int r = 0; r < 4; ++r) rs[r] += __shfl_xor(rs[r], msk);
#pragma unroll
        for (int r = 0; r < 4; ++r) lrow[r] = lrow[r] * alpha[r] + rs[r];
#pragma unroll
        for (int dt = 0; dt < 4; ++dt)
#pragma unroll
            for (int r = 0; r < 4; ++r) oacc[dt][r] *= alpha[r];
        // --- P (C-layout) -> LDS -> A-layout; wave-private strip, in-order DS pipe ---
#pragma unroll
        for (int j = 0; j < 4; ++j)
#pragma unroll
            for (int r = 0; r < 4; ++r)
                Ps[(w * 16 + rq + r) * LDT + j * 16 + cl] = f2bf(sacc[j][r]);
        // --- O strip += P @ V ---
#pragma unroll
        for (int st = 0; st < 2; ++st) {
            bf16x8 pf = ldfrag(&Ps[(w * 16 + fm) * LDT + st * 32 + fk]);
#pragma unroll
            for (int dt = 0; dt < 4; ++dt) {
                bf16x8 vf = ldfrag(&Vs[(dt * 16 + fm) * LDT + st * 32 + fk]);
                oacc[dt] = __builtin_amdgcn_mfma_f32_16x16x32_bf16(pf, vf, oacc[dt], 0, 0, 0);
            }
        }
    }
    // --- epilogue: O = acc / l (bf16) ---
#pragma unroll
    for (int dt = 0; dt < 4; ++dt) {
#pragma unroll
        for (int r = 0; r < 4; ++r) {
            const int q = qt * 64 + w * 16 + rq + r;
            const int d = dt * 16 + cl;
            O[hb + (size_t)q * 512 + d] = f2bf(oacc[dt][r] / lrow[r]);
        }
    }
}

// ---------------- Residual + LayerNorm: out(bf16) = LN(bf16 A + fp32 B) ----------------
// In-place safe on A (row-private; all reads precede writes within the block).
__global__ __launch_bounds__(256) void ln_kernel(const ushort_t* __restrict__ A,
                                                 const float* __restrict__ B,
                                                 const void* __restrict__ g,
                                                 const void* __restrict__ be, size_t pOff,
                                                 ushort_t* __restrict__ out,
                                                 const int* __restrict__ flag) {
    const int isf32 = *flag;
    __shared__ float red[8];
    const int row = blockIdx.x, tid = threadIdx.x;
    const int wave = tid >> 6, lane = tid & 63;
    const size_t off = (size_t)row * 512;
    float v0 = bf2f(A[off + tid]) + B[off + tid];
    float v1 = bf2f(A[off + tid + 256]) + B[off + tid + 256];
    float s = v0 + v1;
#pragma unroll
    for (int o = 32; o; o >>= 1) s += __shfl_xor(s, o);
    if (lane == 0) red[wave] = s;
    __syncthreads();
    const float mean = (red[0] + red[1] + red[2] + red[3]) * (1.f / 512.f);
    const float d0 = v0 - mean, d1 = v1 - mean;
    float ss = d0 * d0 + d1 * d1;
#pragma unroll
    for (int o = 32; o; o >>= 1) ss += __shfl_xor(ss, o);
    if (lane == 0) red[4 + wave] = ss;
    __syncthreads();
    const float var = (red[4] + red[5] + red[6] + red[7]) * (1.f / 511.f);
    const float inv = 1.f / (sqrtf(var) + 1e-6f);
    out[off + tid] = f2bf(ldin(g, pOff + tid, isf32) * d0 * inv + ldin(be, pOff + tid, isf32));
    out[off + tid + 256] = f2bf(ldin(g, pOff + tid + 256, isf32) * d1 * inv + ldin(be, pOff + tid + 256, isf32));
}

// ---------------- final bf16 -> output dtype ----------------
__global__ __launch_bounds__(256) void out_kernel(const ushort_t* __restrict__ X,
                                                  void* __restrict__ out,
                                                  const int* __restrict__ flag) {
    const int isf32 = *flag;
    int i = blockIdx.x * 256 + threadIdx.x;
    if (isf32)
        ((float*)out)[i] = bf2f(X[i]);
    else
        ((ushort_t*)out)[i] = X[i];
}

extern "C" void kernel_launch(void* const* d_in, const int* in_sizes, int n_in,
                              void* d_out, int out_size, void* d_ws, size_t ws_size,
                              hipStream_t stream) {
    const void* x   = d_in[0];
    const int* lens = (const int*)d_in[1];
    const void* Wq  = d_in[2];
    const void* bq  = d_in[3];
    const void* Wk  = d_in[4];
    const void* bk  = d_in[5];
    const void* Wv  = d_in[6];
    const void* bv  = d_in[7];
    const void* Wo  = d_in[8];
    const void* bo  = d_in[9];
    const void* W1  = d_in[10];
    const void* b1  = d_in[11];
    const void* W2  = d_in[12];
    const void* b2  = d_in[13];
    const void* g1  = d_in[14];
    const void* be1 = d_in[15];
    const void* g2  = d_in[16];
    const void* be2 = d_in[17];

    const size_t NE = (size_t)8 * 1024 * 512;  // 4194304 activation elems
    // ws layout (56 MB + 256 B; round-2 proved >= 64 MB available):
    //   flag | B0..B4 (bf16, 8 MB each) | R (fp32, 16 MB)
    int* flag = (int*)d_ws;
    ushort_t* B0 = (ushort_t*)((char*)d_ws + 256);  // X -> Y -> Xnext (LN in-place)
    ushort_t* B1 = B0 + NE;                         // Q ; later F1 (spans B1..B4)
    ushort_t* B2 = B1 + NE;                         // K
    ushort_t* B3 = B2 + NE;                         // V
    ushort_t* B4 = B3 + NE;                         // ATT out
    float*    R  = (float*)(B4 + NE);               // AO / F2 (fp32 residual operand)
    ushort_t* F1 = B1;                              // 8192x2048 bf16 = 32 MB over B1..B4

    dim3 blk(256);
    dim3 gD(512 / 128, 8192 / 128);   // (4, 64)
    dim3 gF(2048 / 128, 8192 / 128);  // (16, 64)

    detect_kernel<<<1, blk, 0, stream>>>((const ushort_t*)x, flag);
    pe_kernel<<<NE / 256, blk, 0, stream>>>(x, B0, flag);
    for (int l = 0; l < 4; ++l) {
        const size_t wD = (size_t)l * 512 * 512;   // dense weight elem offset
        const size_t wF = (size_t)l * 512 * 2048;  // ff weight elem offset
        const size_t bD = (size_t)l * 512;
        const size_t bF = (size_t)l * 2048;

        gemm_kernel<ushort_t, false><<<gD, blk, 0, stream>>>(B0, Wq, wD, bq, bD, B1, 8192, 512, 512, flag);
        gemm_kernel<ushort_t, false><<<gD, blk, 0, stream>>>(B0, Wk, wD, bk, bD, B2, 8192, 512, 512, flag);
        gemm_kernel<ushort_t, false><<<gD, blk, 0, stream>>>(B0, Wv, wD, bv, bD, B3, 8192, 512, 512, flag);
        fattn_kernel<<<dim3(16, 8, 8), blk, 0, stream>>>(B1, B2, B3, lens, B4);
        gemm_kernel<float, false><<<gD, blk, 0, stream>>>(B4, Wo, wD, bo, bD, R, 8192, 512, 512, flag);
        ln_kernel<<<8192, blk, 0, stream>>>(B0, R, g1, be1, bD, B0, flag);   // Y -> B0
        gemm_kernel<ushort_t, true><<<gF, blk, 0, stream>>>(B0, W1, wF, b1, bF, F1, 8192, 512, 2048, flag);
        gemm_kernel<float, false><<<gD, blk, 0, stream>>>(F1, W2, wF, b2, bD, R, 8192, 2048, 512, flag);
        ln_kernel<<<8192, blk, 0, stream>>>(B0, R, g2, be2, bD, B0, flag);   // Xnext -> B0
    }
    out_kernel<<<NE / 256, blk, 0, stream>>>(B0, d_out, flag);
}

// Round 5
// 992.827 us; speedup vs baseline: 8.7365x; 1.3553x over previous
//
#include <hip/hip_runtime.h>
#include <stdint.h>
#include <math.h>

typedef unsigned short ushort_t;
typedef __bf16 bf16x8 __attribute__((ext_vector_type(8)));
typedef unsigned short ushx8 __attribute__((ext_vector_type(8)));
typedef float f32x4 __attribute__((ext_vector_type(4)));

#define DEV static __device__ __forceinline__

DEV float bf2f(ushort_t h) {
    union { unsigned u; float f; } v;
    v.u = ((unsigned)h) << 16;
    return v.f;
}
DEV ushort_t f2bf(float f) {
    union { float f; unsigned u; } v;
    v.f = f;
    unsigned r = v.u + 0x7fffu + ((v.u >> 16) & 1u);
    return (ushort_t)(r >> 16);
}
// runtime-dtype input read (flat element index): flag -> fp32, else bf16 bits
DEV float ldin(const void* p, size_t i, int isf32) {
    return isf32 ? ((const float*)p)[i] : bf2f(((const ushort_t*)p)[i]);
}
DEV bf16x8 ldfrag(const ushort_t* p) {
    return __builtin_bit_cast(bf16x8, *(const ushx8*)p);
}
// async global->LDS, 16 B per lane; LDS dest = wave-uniform base + lane*16
DEV void gld16(const ushort_t* g, ushort_t* l) {
    __builtin_amdgcn_global_load_lds((const __attribute__((address_space(1))) void*)g,
                                     (__attribute__((address_space(3))) void*)l, 16, 0, 0);
}

// ---------------- dtype detector: writes 1 if inputs are fp32 ----------------
__global__ __launch_bounds__(256) void detect_kernel(const ushort_t* __restrict__ x,
                                                     int* __restrict__ flag) {
    __shared__ int bad;
    if (threadIdx.x == 0) bad = 0;
    __syncthreads();
    int b = 0;
#pragma unroll
    for (int i = 0; i < 8; ++i) {
        float v = fabsf(bf2f(x[threadIdx.x * 8 + i]));
        if (!(v <= 16384.f)) b = 1;  // catches huge exponents AND NaN
    }
    if (b) atomicOr(&bad, 1);
    __syncthreads();
    if (threadIdx.x == 0) *flag = bad;
}

// ---------------- per-layer weight pack: W[k][n] -> WT[n][k] bf16, biases -> fp32 ----
// grid: 3072 transpose tiles (32x32) + 18 bias blocks = 3090
__global__ __launch_bounds__(256) void pack_kernel(const void* __restrict__ Wq, const void* __restrict__ Wk,
                                                   const void* __restrict__ Wv, const void* __restrict__ Wo,
                                                   const void* __restrict__ W1, const void* __restrict__ W2,
                                                   const void* __restrict__ bq, const void* __restrict__ bk,
                                                   const void* __restrict__ bv, const void* __restrict__ bo,
                                                   const void* __restrict__ b1, const void* __restrict__ b2,
                                                   size_t wD, size_t wF, size_t bD, size_t bF,
                                                   ushort_t* __restrict__ WqkvT, ushort_t* __restrict__ WoT,
                                                   ushort_t* __restrict__ W1T, ushort_t* __restrict__ W2T,
                                                   float* __restrict__ biasbuf,
                                                   const int* __restrict__ flag) {
    const int isf32 = *flag;
    const int id = blockIdx.x, tid = threadIdx.x;
    if (id < 3072) {
        __shared__ ushort_t T[32][33];
        const void* src;
        size_t soff;
        int srcN, dstK, n0, k0;
        ushort_t* dst;
        if (id < 768) {          // QKV: 48 n-tiles x 16 k-tiles -> WqkvT[1536][512]
            int nt = id >> 4, kt = id & 15;
            int qkv = nt >> 4;
            src = qkv == 0 ? Wq : (qkv == 1 ? Wk : Wv);
            soff = wD; srcN = 512; dstK = 512;
            dst = WqkvT + (size_t)(qkv * 512) * 512;
            n0 = (nt & 15) * 32; k0 = kt * 32;
        } else if (id < 1024) {  // Wo: 16x16 -> WoT[512][512]
            int t = id - 768; int nt = t >> 4, kt = t & 15;
            src = Wo; soff = wD; srcN = 512; dst = WoT; dstK = 512;
            n0 = nt * 32; k0 = kt * 32;
        } else if (id < 2048) {  // W1[512][2048] -> W1T[2048][512]: 64 n x 16 k
            int t = id - 1024; int nt = t >> 4, kt = t & 15;
            src = W1; soff = wF; srcN = 2048; dst = W1T; dstK = 512;
            n0 = nt * 32; k0 = kt * 32;
        } else {                 // W2[2048][512] -> W2T[512][2048]: 16 n x 64 k
            int t = id - 2048; int nt = t >> 6, kt = t & 63;
            src = W2; soff = wF; srcN = 512; dst = W2T; dstK = 2048;
            n0 = nt * 32; k0 = kt * 32;
        }
        const int col = tid & 31, rw = tid >> 5;
#pragma unroll
        for (int p = 0; p < 4; ++p) {
            int kk = rw + p * 8;
            T[kk][col] = f2bf(ldin(src, soff + (size_t)(k0 + kk) * srcN + n0 + col, isf32));
        }
        __syncthreads();
#pragma unroll
        for (int p = 0; p < 4; ++p) {
            int nn = rw + p * 8;
            dst[(size_t)(n0 + nn) * dstK + k0 + col] = T[col][nn];
        }
    } else {
        int j = (id - 3072) * 256 + tid;  // 0..4607: [bq|bk|bv|bo|b1|b2]
        float v;
        if (j < 512) v = ldin(bq, bD + j, isf32);
        else if (j < 1024) v = ldin(bk, bD + j - 512, isf32);
        else if (j < 1536) v = ldin(bv, bD + j - 1024, isf32);
        else if (j < 2048) v = ldin(bo, bD + j - 1536, isf32);
        else if (j < 4096) v = ldin(b1, bF + j - 2048, isf32);
        else v = ldin(b2, bD + j - 4096, isf32);
        biasbuf[j] = v;
    }
}

// ---------------- PE add: X(bf16) = x + pos_encoding ----------------
__global__ __launch_bounds__(256) void pe_kernel(const void* __restrict__ x,
                                                 ushort_t* __restrict__ X,
                                                 const int* __restrict__ flag) {
    const int isf32 = *flag;
    int i = blockIdx.x * 256 + threadIdx.x;
    int d = i & 511;
    int s = (i >> 9) & 1023;
    float freq = expf((float)(d & ~1) * (-9.210340371976184f / 512.f));
    float ang = (float)s * freq;
    float pe = (d & 1) ? cosf(ang) : sinf(ang);
    X[i] = f2bf(ldin(x, i, isf32) + pe);
}

// ---------------- MFMA bf16 GEMM (m97 structure): C = A @ WT^T + bias ----------------
// A[m][k] bf16, Bp[n][k] bf16 (pre-packed), bias fp32. 128x128 tile, BK=32,
// unpadded LDS + global_load_lds width 16, 2-barrier K-loop.
template <typename CT, bool RELU>
__global__ __launch_bounds__(256) void gemm2_kernel(const ushort_t* __restrict__ A,
                                                    const ushort_t* __restrict__ Bp,
                                                    const float* __restrict__ bias,
                                                    CT* __restrict__ C,
                                                    int M, int K, int N) {
    __shared__ ushort_t As[128 * 32];
    __shared__ ushort_t Bs[128 * 32];
    const int tid = threadIdx.x;
    const int bm = blockIdx.y * 128;
    const int bn = blockIdx.x * 128;
    const int w = tid >> 6, lane = tid & 63;
    const int wm = (w >> 1) * 64, wn = (w & 1) * 64;

    f32x4 acc[4][4];
#pragma unroll
    for (int i = 0; i < 4; ++i)
#pragma unroll
        for (int j = 0; j < 4; ++j) acc[i][j] = (f32x4){0.f, 0.f, 0.f, 0.f};

    // staging: chunk c = row*4 + koff/8; issue0 rows 0..63, issue1 rows 64..127
    const int srow = tid >> 2;
    const int sko = (tid & 3) * 8;
    const ushort_t* a0 = A + (size_t)(bm + srow) * K + sko;
    const ushort_t* a1 = A + (size_t)(bm + 64 + srow) * K + sko;
    const ushort_t* b0 = Bp + (size_t)(bn + srow) * K + sko;
    const ushort_t* b1 = Bp + (size_t)(bn + 64 + srow) * K + sko;
    ushort_t* lA0 = As + tid * 8;
    ushort_t* lA1 = As + 2048 + tid * 8;
    ushort_t* lB0 = Bs + tid * 8;
    ushort_t* lB1 = Bs + 2048 + tid * 8;

    const int fm = lane & 15;
    const int fk = (lane >> 4) * 8;

    for (int k0 = 0; k0 < K; k0 += 32) {
        gld16(a0 + k0, lA0);
        gld16(a1 + k0, lA1);
        gld16(b0 + k0, lB0);
        gld16(b1 + k0, lB1);
        __syncthreads();  // drains vmcnt before ds_read
        bf16x8 af[4], bfr[4];
#pragma unroll
        for (int i = 0; i < 4; ++i)
            af[i] = ldfrag(&As[(wm + i * 16 + fm) * 32 + fk]);
#pragma unroll
        for (int j = 0; j < 4; ++j)
            bfr[j] = ldfrag(&Bs[(wn + j * 16 + fm) * 32 + fk]);
#pragma unroll
        for (int i = 0; i < 4; ++i)
#pragma unroll
            for (int j = 0; j < 4; ++j)
                acc[i][j] = __builtin_amdgcn_mfma_f32_16x16x32_bf16(af[i], bfr[j], acc[i][j], 0, 0, 0);
        __syncthreads();  // all consumers done before next staging
    }
    // epilogue: C/D layout col=lane&15, row=(lane>>4)*4+reg
    const int cn = lane & 15;
    const int rq = (lane >> 4) * 4;
#pragma unroll
    for (int j = 0; j < 4; ++j) {
        const int n = bn + wn + j * 16 + cn;
        const float bv = bias[n];
#pragma unroll
        for (int i = 0; i < 4; ++i) {
#pragma unroll
            for (int r = 0; r < 4; ++r) {
                const int m = bm + wm + i * 16 + rq + r;
                float v = acc[i][j][r] + bv;
                if constexpr (RELU) v = fmaxf(v, 0.f);
                if constexpr (sizeof(CT) == 4)
                    ((float*)C)[(size_t)m * N + n] = v;
                else
                    ((ushort_t*)C)[(size_t)m * N + n] = f2bf(v);
            }
        }
    }
}

// ---------------- Flash attention (MFMA, bf16): block = (b,h,64-q tile) ----------------
// QKV packed rows of 1536 (Q|K|V per token). O separate buffer, row stride 512.
__global__ __launch_bounds__(256) void fattn_kernel(const ushort_t* __restrict__ QKV,
                                                    const int* __restrict__ lens,
                                                    ushort_t* __restrict__ O) {
    constexpr int LDT = 72;  // 144 B/row: 16B-aligned b128, 2-way bank alias only (free)
    __shared__ ushort_t Qs[64 * LDT];
    __shared__ ushort_t Ks[64 * LDT];
    __shared__ ushort_t Vs[64 * LDT];  // transposed: Vs[d][key]
    __shared__ ushort_t Ps[64 * LDT];  // wave-private 16-row strips
    const int qt = blockIdx.x, h = blockIdx.y, b = blockIdx.z;
    const int tid = threadIdx.x, w = tid >> 6, L = tid & 63;
    const int len = lens[b];
    const size_t hb = ((size_t)b * 1024) * 1536 + (size_t)h * 64;
    const int fm = L & 15;            // frag row (A/B m/n)
    const int fk = (L >> 4) * 8;      // frag k offset
    const int cl = L & 15;            // C col
    const int rq = (L >> 4) * 4;      // C row base

    const int srow = tid >> 2;        // 0..63 staging row
    const int sc0 = (tid & 3) * 16;   // staging col base

    // stage Q tile (raw; 1/sqrt(64) applied post-MFMA in fp32)
    {
        const ushx8* qp = (const ushx8*)(QKV + hb + (size_t)(qt * 64 + srow) * 1536 + sc0);
        *(ushx8*)&Qs[srow * LDT + sc0] = qp[0];
        *(ushx8*)&Qs[srow * LDT + sc0 + 8] = qp[1];
    }

    float mrow[4], lrow[4];
    f32x4 oacc[4];
#pragma unroll
    for (int r = 0; r < 4; ++r) { mrow[r] = -1e30f; lrow[r] = 0.f; }
#pragma unroll
    for (int dt = 0; dt < 4; ++dt) oacc[dt] = (f32x4){0.f, 0.f, 0.f, 0.f};

    const int nkb = (len + 63) >> 6;
    for (int kb = 0; kb < nkb; ++kb) {
        __syncthreads();  // prior consumers done before re-staging Ks/Vs
        {
            const ushx8* kp = (const ushx8*)(QKV + hb + 512 + (size_t)(kb * 64 + srow) * 1536 + sc0);
            const ushx8* vp = (const ushx8*)(QKV + hb + 1024 + (size_t)(kb * 64 + srow) * 1536 + sc0);
            *(ushx8*)&Ks[srow * LDT + sc0] = kp[0];
            *(ushx8*)&Ks[srow * LDT + sc0 + 8] = kp[1];
            ushx8 v0 = vp[0], v1 = vp[1];
#pragma unroll
            for (int i = 0; i < 8; ++i) Vs[(sc0 + i) * LDT + srow] = v0[i];
#pragma unroll
            for (int i = 0; i < 8; ++i) Vs[(sc0 + 8 + i) * LDT + srow] = v1[i];
        }
        __syncthreads();
        // --- S strip (16 q x 64 k) = Q strip @ K^T ---
        f32x4 sacc[4];
#pragma unroll
        for (int j = 0; j < 4; ++j) sacc[j] = (f32x4){0.f, 0.f, 0.f, 0.f};
#pragma unroll
        for (int st = 0; st < 2; ++st) {
            bf16x8 af = ldfrag(&Qs[(w * 16 + fm) * LDT + st * 32 + fk]);
#pragma unroll
            for (int j = 0; j < 4; ++j) {
                bf16x8 bf = ldfrag(&Ks[(j * 16 + fm) * LDT + st * 32 + fk]);
                sacc[j] = __builtin_amdgcn_mfma_f32_16x16x32_bf16(af, bf, sacc[j], 0, 0, 0);
            }
        }
        // --- scale + mask + online softmax (rows live in 16-lane col groups) ---
        const int colb = kb * 64;
        float nm[4] = {-1e30f, -1e30f, -1e30f, -1e30f};
#pragma unroll
        for (int j = 0; j < 4; ++j) {
            const bool mk = (colb + j * 16 + cl) >= len;
#pragma unroll
            for (int r = 0; r < 4; ++r) {
                float s = mk ? -1e30f : sacc[j][r] * 0.125f;
                sacc[j][r] = s;
                nm[r] = fmaxf(nm[r], s);
            }
        }
#pragma unroll
        for (int msk = 1; msk <= 8; msk <<= 1)
#pragma unroll
            for (int r = 0; r < 4; ++r) nm[r] = fmaxf(nm[r], __shfl_xor(nm[r], msk));
        float alpha[4], rs[4];
#pragma unroll
        for (int r = 0; r < 4; ++r) {
            float mn = fmaxf(mrow[r], nm[r]);
            alpha[r] = __expf(mrow[r] - mn);
            mrow[r] = mn;
            rs[r] = 0.f;
        }
#pragma unroll
        for (int j = 0; j < 4; ++j) {
            const bool mk = (colb + j * 16 + cl) >= len;
#pragma unroll
            for (int r = 0; r < 4; ++r) {
                float p = mk ? 0.f : __expf(sacc[j][r] - mrow[r]);
                sacc[j][r] = p;
                rs[r] += p;
            }
        }
#pragma unroll
        for (int msk = 1; msk <= 8; msk <<= 1)
#pragma unroll
            for (int r = 0; r < 4; ++r) rs[r] += __shfl_xor(rs[r], msk);
#pragma unroll
        for (int r = 0; r < 4; ++r) lrow[r] = lrow[r] * alpha[r] + rs[r];
#pragma unroll
        for (int dt = 0; dt < 4; ++dt)
#pragma unroll
            for (int r = 0; r < 4; ++r) oacc[dt][r] *= alpha[r];
        // --- P (C-layout) -> LDS -> A-layout; wave-private strip, in-order DS pipe ---
#pragma unroll
        for (int j = 0; j < 4; ++j)
#pragma unroll
            for (int r = 0; r < 4; ++r)
                Ps[(w * 16 + rq + r) * LDT + j * 16 + cl] = f2bf(sacc[j][r]);
        // --- O strip += P @ V ---
#pragma unroll
        for (int st = 0; st < 2; ++st) {
            bf16x8 pf = ldfrag(&Ps[(w * 16 + fm) * LDT + st * 32 + fk]);
#pragma unroll
            for (int dt = 0; dt < 4; ++dt) {
                bf16x8 vf = ldfrag(&Vs[(dt * 16 + fm) * LDT + st * 32 + fk]);
                oacc[dt] = __builtin_amdgcn_mfma_f32_16x16x32_bf16(pf, vf, oacc[dt], 0, 0, 0);
            }
        }
    }
    // --- epilogue: O = acc / l (bf16), row stride 512 ---
    const size_t ob = ((size_t)b * 1024) * 512 + (size_t)h * 64;
#pragma unroll
    for (int dt = 0; dt < 4; ++dt) {
#pragma unroll
        for (int r = 0; r < 4; ++r) {
            const int q = qt * 64 + w * 16 + rq + r;
            const int d = dt * 16 + cl;
            O[ob + (size_t)q * 512 + d] = f2bf(oacc[dt][r] / lrow[r]);
        }
    }
}

// ---------------- Residual + LayerNorm: out(bf16) = LN(bf16 A + fp32 B) ----------------
__global__ __launch_bounds__(256) void ln_kernel(const ushort_t* __restrict__ A,
                                                 const float* __restrict__ B,
                                                 const void* __restrict__ g,
                                                 const void* __restrict__ be, size_t pOff,
                                                 ushort_t* __restrict__ out,
                                                 const int* __restrict__ flag) {
    const int isf32 = *flag;
    __shared__ float red[8];
    const int row = blockIdx.x, tid = threadIdx.x;
    const int wave = tid >> 6, lane = tid & 63;
    const size_t off = (size_t)row * 512;
    float v0 = bf2f(A[off + tid]) + B[off + tid];
    float v1 = bf2f(A[off + tid + 256]) + B[off + tid + 256];
    float s = v0 + v1;
#pragma unroll
    for (int o = 32; o; o >>= 1) s += __shfl_xor(s, o);
    if (lane == 0) red[wave] = s;
    __syncthreads();
    const float mean = (red[0] + red[1] + red[2] + red[3]) * (1.f / 512.f);
    const float d0 = v0 - mean, d1 = v1 - mean;
    float ss = d0 * d0 + d1 * d1;
#pragma unroll
    for (int o = 32; o; o >>= 1) ss += __shfl_xor(ss, o);
    if (lane == 0) red[4 + wave] = ss;
    __syncthreads();
    const float var = (red[4] + red[5] + red[6] + red[7]) * (1.f / 511.f);
    const float inv = 1.f / (sqrtf(var) + 1e-6f);
    out[off + tid] = f2bf(ldin(g, pOff + tid, isf32) * d0 * inv + ldin(be, pOff + tid, isf32));
    out[off + tid + 256] = f2bf(ldin(g, pOff + tid + 256, isf32) * d1 * inv + ldin(be, pOff + tid + 256, isf32));
}

// ---------------- final bf16 -> output dtype ----------------
__global__ __launch_bounds__(256) void out_kernel(const ushort_t* __restrict__ X,
                                                  void* __restrict__ out,
                                                  const int* __restrict__ flag) {
    const int isf32 = *flag;
    int i = blockIdx.x * 256 + threadIdx.x;
    if (isf32)
        ((float*)out)[i] = bf2f(X[i]);
    else
        ((ushort_t*)out)[i] = X[i];
}

extern "C" void kernel_launch(void* const* d_in, const int* in_sizes, int n_in,
                              void* d_out, int out_size, void* d_ws, size_t ws_size,
                              hipStream_t stream) {
    const void* x   = d_in[0];
    const int* lens = (const int*)d_in[1];
    const void* Wq  = d_in[2];
    const void* bq  = d_in[3];
    const void* Wk  = d_in[4];
    const void* bk  = d_in[5];
    const void* Wv  = d_in[6];
    const void* bv  = d_in[7];
    const void* Wo  = d_in[8];
    const void* bo  = d_in[9];
    const void* W1  = d_in[10];
    const void* b1  = d_in[11];
    const void* W2  = d_in[12];
    const void* b2  = d_in[13];
    const void* g1  = d_in[14];
    const void* be1 = d_in[15];
    const void* g2  = d_in[16];
    const void* be2 = d_in[17];

    const size_t NE = (size_t)8 * 1024 * 512;  // 4 M activation elems
    char* base = (char*)d_ws;
    // ws layout (exactly 64 MB + small header; 64.25 MB proven available):
    int*      flag    = (int*)base;                         // 256 B
    ushort_t* WqkvT   = (ushort_t*)(base + 256);            // 1.5 MB  [1536][512]
    ushort_t* WoT     = (ushort_t*)(base + 1573120);        // 0.5 MB  [512][512]
    ushort_t* W1T     = (ushort_t*)(base + 2097408);        // 2 MB    [2048][512]
    ushort_t* W2T     = (ushort_t*)(base + 4194560);        // 2 MB    [512][2048]
    float*    biasbuf = (float*)(base + 6291712);           // 18 KB   [qkv|o|1|2]
    ushort_t* B123    = (ushort_t*)(base + 8388608);        // 24 MB   QKV (stride 1536)
    ushort_t* B4      = (ushort_t*)(base + 33554432);       // 8 MB    ATT out
    ushort_t* B0      = (ushort_t*)(base + 41943040);       // 8 MB    X / Y
    float*    R       = (float*)(base + 50331648);          // 16 MB   fp32 residual operand
    ushort_t* F1      = B123;                               // 32 MB   spans B123+B4

    dim3 blk(256);
    dim3 gQKV(1536 / 128, 8192 / 128);  // (12, 64)
    dim3 gD(512 / 128, 8192 / 128);     // (4, 64)
    dim3 gF(2048 / 128, 8192 / 128);    // (16, 64)

    detect_kernel<<<1, blk, 0, stream>>>((const ushort_t*)x, flag);
    pe_kernel<<<NE / 256, blk, 0, stream>>>(x, B0, flag);
    for (int l = 0; l < 4; ++l) {
        const size_t wD = (size_t)l * 512 * 512;
        const size_t wF = (size_t)l * 512 * 2048;
        const size_t bD = (size_t)l * 512;
        const size_t bF = (size_t)l * 2048;

        pack_kernel<<<3090, blk, 0, stream>>>(Wq, Wk, Wv, Wo, W1, W2,
                                              bq, bk, bv, bo, b1, b2,
                                              wD, wF, bD, bF,
                                              WqkvT, WoT, W1T, W2T, biasbuf, flag);
        gemm2_kernel<ushort_t, false><<<gQKV, blk, 0, stream>>>(B0, WqkvT, biasbuf, B123, 8192, 512, 1536);
        fattn_kernel<<<dim3(16, 8, 8), blk, 0, stream>>>(B123, lens, B4);
        gemm2_kernel<float, false><<<gD, blk, 0, stream>>>(B4, WoT, biasbuf + 1536, R, 8192, 512, 512);
        ln_kernel<<<8192, blk, 0, stream>>>(B0, R, g1, be1, bD, B0, flag);   // Y -> B0
        gemm2_kernel<ushort_t, true><<<gF, blk, 0, stream>>>(B0, W1T, biasbuf + 2048, F1, 8192, 512, 2048);
        gemm2_kernel<float, false><<<gD, blk, 0, stream>>>(F1, W2T, biasbuf + 4096, R, 8192, 2048, 512);
        ln_kernel<<<8192, blk, 0, stream>>>(B0, R, g2, be2, bD, B0, flag);   // Xnext -> B0
    }
    out_kernel<<<NE / 256, blk, 0, stream>>>(B0, d_out, flag);
}

// Round 6
// 933.345 us; speedup vs baseline: 9.2933x; 1.0637x over previous
//
#include <hip/hip_runtime.h>
#include <stdint.h>
#include <math.h>

typedef unsigned short ushort_t;
typedef __bf16 bf16x8 __attribute__((ext_vector_type(8)));
typedef unsigned short ushx8 __attribute__((ext_vector_type(8)));
typedef float f32x4 __attribute__((ext_vector_type(4)));

#define DEV static __device__ __forceinline__

DEV float bf2f(ushort_t h) {
    union { unsigned u; float f; } v;
    v.u = ((unsigned)h) << 16;
    return v.f;
}
DEV ushort_t f2bf(float f) {
    union { float f; unsigned u; } v;
    v.f = f;
    unsigned r = v.u + 0x7fffu + ((v.u >> 16) & 1u);
    return (ushort_t)(r >> 16);
}
// runtime-dtype input read (flat element index): flag -> fp32, else bf16 bits
DEV float ldin(const void* p, size_t i, int isf32) {
    return isf32 ? ((const float*)p)[i] : bf2f(((const ushort_t*)p)[i]);
}
DEV bf16x8 ldfrag(const ushort_t* p) {
    return __builtin_bit_cast(bf16x8, *(const ushx8*)p);
}
// async global->LDS, 16 B per lane; LDS dest = wave-uniform base + lane*16
DEV void gld16(const ushort_t* g, ushort_t* l) {
    __builtin_amdgcn_global_load_lds((const __attribute__((address_space(1))) void*)g,
                                     (__attribute__((address_space(3))) void*)l, 16, 0, 0);
}

// ---------------- dtype detector: writes 1 if inputs are fp32 ----------------
__global__ __launch_bounds__(256) void detect_kernel(const ushort_t* __restrict__ x,
                                                     int* __restrict__ flag) {
    __shared__ int bad;
    if (threadIdx.x == 0) bad = 0;
    __syncthreads();
    int b = 0;
#pragma unroll
    for (int i = 0; i < 8; ++i) {
        float v = fabsf(bf2f(x[threadIdx.x * 8 + i]));
        if (!(v <= 16384.f)) b = 1;  // catches huge exponents AND NaN
    }
    if (b) atomicOr(&bad, 1);
    __syncthreads();
    if (threadIdx.x == 0) *flag = bad;
}

// ---------------- per-layer weight pack: W[k][n] -> WT[n][k] bf16, biases -> fp32 ----
__global__ __launch_bounds__(256) void pack_kernel(const void* __restrict__ Wq, const void* __restrict__ Wk,
                                                   const void* __restrict__ Wv, const void* __restrict__ Wo,
                                                   const void* __restrict__ W1, const void* __restrict__ W2,
                                                   const void* __restrict__ bq, const void* __restrict__ bk,
                                                   const void* __restrict__ bv, const void* __restrict__ bo,
                                                   const void* __restrict__ b1, const void* __restrict__ b2,
                                                   size_t wD, size_t wF, size_t bD, size_t bF,
                                                   ushort_t* __restrict__ WqkvT, ushort_t* __restrict__ WoT,
                                                   ushort_t* __restrict__ W1T, ushort_t* __restrict__ W2T,
                                                   float* __restrict__ biasbuf,
                                                   const int* __restrict__ flag) {
    const int isf32 = *flag;
    const int id = blockIdx.x, tid = threadIdx.x;
    if (id < 3072) {
        __shared__ ushort_t T[32][33];
        const void* src;
        size_t soff;
        int srcN, dstK, n0, k0;
        ushort_t* dst;
        if (id < 768) {          // QKV -> WqkvT[1536][512]
            int nt = id >> 4, kt = id & 15;
            int qkv = nt >> 4;
            src = qkv == 0 ? Wq : (qkv == 1 ? Wk : Wv);
            soff = wD; srcN = 512; dstK = 512;
            dst = WqkvT + (size_t)(qkv * 512) * 512;
            n0 = (nt & 15) * 32; k0 = kt * 32;
        } else if (id < 1024) {  // Wo -> WoT[512][512]
            int t = id - 768; int nt = t >> 4, kt = t & 15;
            src = Wo; soff = wD; srcN = 512; dst = WoT; dstK = 512;
            n0 = nt * 32; k0 = kt * 32;
        } else if (id < 2048) {  // W1[512][2048] -> W1T[2048][512]
            int t = id - 1024; int nt = t >> 4, kt = t & 15;
            src = W1; soff = wF; srcN = 2048; dst = W1T; dstK = 512;
            n0 = nt * 32; k0 = kt * 32;
        } else {                 // W2[2048][512] -> W2T[512][2048]
            int t = id - 2048; int nt = t >> 6, kt = t & 63;
            src = W2; soff = wF; srcN = 512; dst = W2T; dstK = 2048;
            n0 = nt * 32; k0 = kt * 32;
        }
        const int col = tid & 31, rw = tid >> 5;
#pragma unroll
        for (int p = 0; p < 4; ++p) {
            int kk = rw + p * 8;
            T[kk][col] = f2bf(ldin(src, soff + (size_t)(k0 + kk) * srcN + n0 + col, isf32));
        }
        __syncthreads();
#pragma unroll
        for (int p = 0; p < 4; ++p) {
            int nn = rw + p * 8;
            dst[(size_t)(n0 + nn) * dstK + k0 + col] = T[col][nn];
        }
    } else {
        int j = (id - 3072) * 256 + tid;  // 0..4607: [bq|bk|bv|bo|b1|b2]
        float v;
        if (j < 512) v = ldin(bq, bD + j, isf32);
        else if (j < 1024) v = ldin(bk, bD + j - 512, isf32);
        else if (j < 1536) v = ldin(bv, bD + j - 1024, isf32);
        else if (j < 2048) v = ldin(bo, bD + j - 1536, isf32);
        else if (j < 4096) v = ldin(b1, bF + j - 2048, isf32);
        else v = ldin(b2, bD + j - 4096, isf32);
        biasbuf[j] = v;
    }
}

// ---------------- PE add: X(bf16) = x + pos_encoding ----------------
__global__ __launch_bounds__(256) void pe_kernel(const void* __restrict__ x,
                                                 ushort_t* __restrict__ X,
                                                 const int* __restrict__ flag) {
    const int isf32 = *flag;
    int i = blockIdx.x * 256 + threadIdx.x;
    int d = i & 511;
    int s = (i >> 9) & 1023;
    float freq = expf((float)(d & ~1) * (-9.210340371976184f / 512.f));
    float ang = (float)s * freq;
    float pe = (d & 1) ? cosf(ang) : sinf(ang);
    X[i] = f2bf(ldin(x, i, isf32) + pe);
}

// ---------------- MFMA bf16 GEMM (m97 structure) ----------------
template <typename CT, bool RELU>
__global__ __launch_bounds__(256) void gemm2_kernel(const ushort_t* __restrict__ A,
                                                    const ushort_t* __restrict__ Bp,
                                                    const float* __restrict__ bias,
                                                    CT* __restrict__ C,
                                                    int M, int K, int N) {
    __shared__ ushort_t As[128 * 32];
    __shared__ ushort_t Bs[128 * 32];
    const int tid = threadIdx.x;
    const int bm = blockIdx.y * 128;
    const int bn = blockIdx.x * 128;
    const int w = tid >> 6, lane = tid & 63;
    const int wm = (w >> 1) * 64, wn = (w & 1) * 64;

    f32x4 acc[4][4];
#pragma unroll
    for (int i = 0; i < 4; ++i)
#pragma unroll
        for (int j = 0; j < 4; ++j) acc[i][j] = (f32x4){0.f, 0.f, 0.f, 0.f};

    const int srow = tid >> 2;
    const int sko = (tid & 3) * 8;
    const ushort_t* a0 = A + (size_t)(bm + srow) * K + sko;
    const ushort_t* a1 = A + (size_t)(bm + 64 + srow) * K + sko;
    const ushort_t* b0 = Bp + (size_t)(bn + srow) * K + sko;
    const ushort_t* b1 = Bp + (size_t)(bn + 64 + srow) * K + sko;
    ushort_t* lA0 = As + tid * 8;
    ushort_t* lA1 = As + 2048 + tid * 8;
    ushort_t* lB0 = Bs + tid * 8;
    ushort_t* lB1 = Bs + 2048 + tid * 8;

    const int fm = lane & 15;
    const int fk = (lane >> 4) * 8;

    for (int k0 = 0; k0 < K; k0 += 32) {
        gld16(a0 + k0, lA0);
        gld16(a1 + k0, lA1);
        gld16(b0 + k0, lB0);
        gld16(b1 + k0, lB1);
        __syncthreads();
        bf16x8 af[4], bfr[4];
#pragma unroll
        for (int i = 0; i < 4; ++i)
            af[i] = ldfrag(&As[(wm + i * 16 + fm) * 32 + fk]);
#pragma unroll
        for (int j = 0; j < 4; ++j)
            bfr[j] = ldfrag(&Bs[(wn + j * 16 + fm) * 32 + fk]);
#pragma unroll
        for (int i = 0; i < 4; ++i)
#pragma unroll
            for (int j = 0; j < 4; ++j)
                acc[i][j] = __builtin_amdgcn_mfma_f32_16x16x32_bf16(af[i], bfr[j], acc[i][j], 0, 0, 0);
        __syncthreads();
    }
    const int cn = lane & 15;
    const int rq = (lane >> 4) * 4;
#pragma unroll
    for (int j = 0; j < 4; ++j) {
        const int n = bn + wn + j * 16 + cn;
        const float bv = bias[n];
#pragma unroll
        for (int i = 0; i < 4; ++i) {
#pragma unroll
            for (int r = 0; r < 4; ++r) {
                const int m = bm + wm + i * 16 + rq + r;
                float v = acc[i][j][r] + bv;
                if constexpr (RELU) v = fmaxf(v, 0.f);
                if constexpr (sizeof(CT) == 4)
                    ((float*)C)[(size_t)m * N + n] = v;
                else
                    ((ushort_t*)C)[(size_t)m * N + n] = f2bf(v);
            }
        }
    }
}

// ---------------- V transpose: VT[b][h][d][s] from QKV V-part ----------------
// block = (s-tile, h, b): 64 s x 64 d. Coalesced 128 B stores along s.
__global__ __launch_bounds__(256) void vt_kernel(const ushort_t* __restrict__ QKV,
                                                 ushort_t* __restrict__ VT) {
    const int st = blockIdx.x, h = blockIdx.y, b = blockIdx.z;
    const int tid = threadIdx.x;
    const int s = st * 64 + (tid & 63);
    const int dc = (tid >> 6) * 16;
    const ushort_t* src = QKV + ((size_t)b * 1024 + s) * 1536 + 1024 + h * 64 + dc;
    ushx8 r0 = *(const ushx8*)src;
    ushx8 r1 = *(const ushx8*)(src + 8);
    ushort_t* dst = VT + (((size_t)(b * 8 + h)) * 64 + dc) * 1024 + s;
#pragma unroll
    for (int i = 0; i < 8; ++i) dst[(size_t)i * 1024] = r0[i];
#pragma unroll
    for (int i = 0; i < 8; ++i) dst[(size_t)(8 + i) * 1024] = r1[i];
}

// ---------------- Flash attention (MFMA, async staging, flat softmax) ----------------
// QKV rows of 1536 (Q|K|V). VT[b][h][d][s]. O row stride 512.
__global__ __launch_bounds__(256) void fattn_kernel(const ushort_t* __restrict__ QKV,
                                                    const ushort_t* __restrict__ VT,
                                                    const int* __restrict__ lens,
                                                    ushort_t* __restrict__ O) {
    __shared__ ushort_t Qs[64 * 64];
    __shared__ ushort_t Ks[64 * 64];
    __shared__ ushort_t Vs[64 * 64];   // [d][key]
    __shared__ ushort_t Ps[64 * 72];   // padded; wave-private strips
    const int qt = blockIdx.x, h = blockIdx.y, b = blockIdx.z;
    const int tid = threadIdx.x, w = tid >> 6, L = tid & 63;
    const int len = lens[b];
    const size_t qkvb = ((size_t)b * 1024) * 1536 + (size_t)h * 64;
    const size_t vtb = ((size_t)(b * 8 + h)) * 64 * 1024;
    const int fm = L & 15, fk = (L >> 4) * 8;
    const int cl = L & 15, rq = (L >> 4) * 4;
    const int sr = tid >> 3, sc8 = (tid & 7) * 8;

    // stage Q tile (async; drained by first in-loop barrier)
    gld16(QKV + qkvb + (size_t)(qt * 64 + sr) * 1536 + sc8, Qs + tid * 8);
    gld16(QKV + qkvb + (size_t)(qt * 64 + 32 + sr) * 1536 + sc8, Qs + 2048 + tid * 8);

    float rs[4] = {0.f, 0.f, 0.f, 0.f};   // per-lane partial row sums
    f32x4 oacc[4];
#pragma unroll
    for (int dt = 0; dt < 4; ++dt) oacc[dt] = (f32x4){0.f, 0.f, 0.f, 0.f};
    const float sscale = 0.125f * 1.44269504f;  // (1/sqrt(64)) * log2(e)

    const int nkb = (len + 63) >> 6;
    for (int kb = 0; kb < nkb; ++kb) {
        __syncthreads();  // prev-iter consumers done
        gld16(QKV + qkvb + 512 + (size_t)(kb * 64 + sr) * 1536 + sc8, Ks + tid * 8);
        gld16(QKV + qkvb + 512 + (size_t)(kb * 64 + 32 + sr) * 1536 + sc8, Ks + 2048 + tid * 8);
        gld16(VT + vtb + (size_t)sr * 1024 + kb * 64 + sc8, Vs + tid * 8);
        gld16(VT + vtb + (size_t)(32 + sr) * 1024 + kb * 64 + sc8, Vs + 2048 + tid * 8);
        __syncthreads();  // vmcnt drained + published
        // --- S strip (16 q x 64 k) = Q strip @ K^T ---
        f32x4 sacc[4];
#pragma unroll
        for (int j = 0; j < 4; ++j) sacc[j] = (f32x4){0.f, 0.f, 0.f, 0.f};
#pragma unroll
        for (int st = 0; st < 2; ++st) {
            bf16x8 af = ldfrag(&Qs[(w * 16 + fm) * 64 + st * 32 + fk]);
#pragma unroll
            for (int j = 0; j < 4; ++j) {
                bf16x8 bf = ldfrag(&Ks[(j * 16 + fm) * 64 + st * 32 + fk]);
                sacc[j] = __builtin_amdgcn_mfma_f32_16x16x32_bf16(af, bf, sacc[j], 0, 0, 0);
            }
        }
        // --- flat softmax accumulation: p = 2^(s*scale); masked -> 0 ---
        const int colb = kb * 64;
#pragma unroll
        for (int j = 0; j < 4; ++j) {
            const bool mk = (colb + j * 16 + cl) >= len;
#pragma unroll
            for (int r = 0; r < 4; ++r) {
                float p = mk ? 0.f : exp2f(sacc[j][r] * sscale);
                sacc[j][r] = p;
                rs[r] += p;
            }
        }
        // --- P (C-layout) -> LDS -> A-layout; wave-private strip ---
#pragma unroll
        for (int j = 0; j < 4; ++j)
#pragma unroll
            for (int r = 0; r < 4; ++r)
                Ps[(w * 16 + rq + r) * 72 + j * 16 + cl] = f2bf(sacc[j][r]);
        // --- O strip += P @ V ---
#pragma unroll
        for (int st = 0; st < 2; ++st) {
            bf16x8 pf = ldfrag(&Ps[(w * 16 + fm) * 72 + st * 32 + fk]);
#pragma unroll
            for (int dt = 0; dt < 4; ++dt) {
                bf16x8 vf = ldfrag(&Vs[(dt * 16 + fm) * 64 + st * 32 + fk]);
                oacc[dt] = __builtin_amdgcn_mfma_f32_16x16x32_bf16(pf, vf, oacc[dt], 0, 0, 0);
            }
        }
    }
    // --- reduce row sums across the 16-lane col groups, then divide ---
#pragma unroll
    for (int msk = 1; msk <= 8; msk <<= 1)
#pragma unroll
        for (int r = 0; r < 4; ++r) rs[r] += __shfl_xor(rs[r], msk);
    float inv[4];
#pragma unroll
    for (int r = 0; r < 4; ++r) inv[r] = 1.f / rs[r];
    const size_t ob = ((size_t)b * 1024) * 512 + (size_t)h * 64;
#pragma unroll
    for (int dt = 0; dt < 4; ++dt) {
#pragma unroll
        for (int r = 0; r < 4; ++r) {
            const int q = qt * 64 + w * 16 + rq + r;
            const int d = dt * 16 + cl;
            O[ob + (size_t)q * 512 + d] = f2bf(oacc[dt][r] * inv[r]);
        }
    }
}

// ---------------- Residual + LayerNorm: out(bf16) = LN(bf16 A + fp32 B) ----------------
__global__ __launch_bounds__(256) void ln_kernel(const ushort_t* __restrict__ A,
                                                 const float* __restrict__ B,
                                                 const void* __restrict__ g,
                                                 const void* __restrict__ be, size_t pOff,
                                                 ushort_t* __restrict__ out,
                                                 const int* __restrict__ flag) {
    const int isf32 = *flag;
    __shared__ float red[8];
    const int row = blockIdx.x, tid = threadIdx.x;
    const int wave = tid >> 6, lane = tid & 63;
    const size_t off = (size_t)row * 512;
    float v0 = bf2f(A[off + tid]) + B[off + tid];
    float v1 = bf2f(A[off + tid + 256]) + B[off + tid + 256];
    float s = v0 + v1;
#pragma unroll
    for (int o = 32; o; o >>= 1) s += __shfl_xor(s, o);
    if (lane == 0) red[wave] = s;
    __syncthreads();
    const float mean = (red[0] + red[1] + red[2] + red[3]) * (1.f / 512.f);
    const float d0 = v0 - mean, d1 = v1 - mean;
    float ss = d0 * d0 + d1 * d1;
#pragma unroll
    for (int o = 32; o; o >>= 1) ss += __shfl_xor(ss, o);
    if (lane == 0) red[4 + wave] = ss;
    __syncthreads();
    const float var = (red[4] + red[5] + red[6] + red[7]) * (1.f / 511.f);
    const float inv = 1.f / (sqrtf(var) + 1e-6f);
    out[off + tid] = f2bf(ldin(g, pOff + tid, isf32) * d0 * inv + ldin(be, pOff + tid, isf32));
    out[off + tid + 256] = f2bf(ldin(g, pOff + tid + 256, isf32) * d1 * inv + ldin(be, pOff + tid + 256, isf32));
}

// ---------------- final bf16 -> output dtype ----------------
__global__ __launch_bounds__(256) void out_kernel(const ushort_t* __restrict__ X,
                                                  void* __restrict__ out,
                                                  const int* __restrict__ flag) {
    const int isf32 = *flag;
    int i = blockIdx.x * 256 + threadIdx.x;
    if (isf32)
        ((float*)out)[i] = bf2f(X[i]);
    else
        ((ushort_t*)out)[i] = X[i];
}

extern "C" void kernel_launch(void* const* d_in, const int* in_sizes, int n_in,
                              void* d_out, int out_size, void* d_ws, size_t ws_size,
                              hipStream_t stream) {
    const void* x   = d_in[0];
    const int* lens = (const int*)d_in[1];
    const void* Wq  = d_in[2];
    const void* bq  = d_in[3];
    const void* Wk  = d_in[4];
    const void* bk  = d_in[5];
    const void* Wv  = d_in[6];
    const void* bv  = d_in[7];
    const void* Wo  = d_in[8];
    const void* bo  = d_in[9];
    const void* W1  = d_in[10];
    const void* b1  = d_in[11];
    const void* W2  = d_in[12];
    const void* b2  = d_in[13];
    const void* g1  = d_in[14];
    const void* be1 = d_in[15];
    const void* g2  = d_in[16];
    const void* be2 = d_in[17];

    const size_t NE = (size_t)8 * 1024 * 512;
    char* base = (char*)d_ws;
    int*      flag    = (int*)base;                         // 256 B
    ushort_t* WqkvT   = (ushort_t*)(base + 256);            // 1.5 MB
    ushort_t* WoT     = (ushort_t*)(base + 1573120);        // 0.5 MB
    ushort_t* W1T     = (ushort_t*)(base + 2097408);        // 2 MB
    ushort_t* W2T     = (ushort_t*)(base + 4194560);        // 2 MB
    float*    biasbuf = (float*)(base + 6291712);           // 18 KB
    ushort_t* B123    = (ushort_t*)(base + 8388608);        // 24 MB  QKV (stride 1536)
    ushort_t* B4      = (ushort_t*)(base + 33554432);       // 8 MB   ATT out
    ushort_t* B0      = (ushort_t*)(base + 41943040);       // 8 MB   X / Y
    float*    R       = (float*)(base + 50331648);          // 16 MB  fp32 residual operand
    ushort_t* VT      = (ushort_t*)R;                       // 8 MB, dead before Wo-GEMM writes R
    ushort_t* F1      = B123;                               // 32 MB spans B123+B4

    dim3 blk(256);
    dim3 gQKV(1536 / 128, 8192 / 128);
    dim3 gD(512 / 128, 8192 / 128);
    dim3 gF(2048 / 128, 8192 / 128);

    detect_kernel<<<1, blk, 0, stream>>>((const ushort_t*)x, flag);
    pe_kernel<<<NE / 256, blk, 0, stream>>>(x, B0, flag);
    for (int l = 0; l < 4; ++l) {
        const size_t wD = (size_t)l * 512 * 512;
        const size_t wF = (size_t)l * 512 * 2048;
        const size_t bD = (size_t)l * 512;
        const size_t bF = (size_t)l * 2048;

        pack_kernel<<<3090, blk, 0, stream>>>(Wq, Wk, Wv, Wo, W1, W2,
                                              bq, bk, bv, bo, b1, b2,
                                              wD, wF, bD, bF,
                                              WqkvT, WoT, W1T, W2T, biasbuf, flag);
        gemm2_kernel<ushort_t, false><<<gQKV, blk, 0, stream>>>(B0, WqkvT, biasbuf, B123, 8192, 512, 1536);
        vt_kernel<<<dim3(16, 8, 8), blk, 0, stream>>>(B123, VT);
        fattn_kernel<<<dim3(16, 8, 8), blk, 0, stream>>>(B123, VT, lens, B4);
        gemm2_kernel<float, false><<<gD, blk, 0, stream>>>(B4, WoT, biasbuf + 1536, R, 8192, 512, 512);
        ln_kernel<<<8192, blk, 0, stream>>>(B0, R, g1, be1, bD, B0, flag);
        gemm2_kernel<ushort_t, true><<<gF, blk, 0, stream>>>(B0, W1T, biasbuf + 2048, F1, 8192, 512, 2048);
        gemm2_kernel<float, false><<<gD, blk, 0, stream>>>(F1, W2T, biasbuf + 4096, R, 8192, 2048, 512);
        ln_kernel<<<8192, blk, 0, stream>>>(B0, R, g2, be2, bD, B0, flag);
    }
    out_kernel<<<NE / 256, blk, 0, stream>>>(B0, d_out, flag);
}

// Round 7
// 892.159 us; speedup vs baseline: 9.7223x; 1.0462x over previous
//
#include <hip/hip_runtime.h>
#include <stdint.h>
#include <math.h>

typedef unsigned short ushort_t;
typedef __bf16 bf16x8 __attribute__((ext_vector_type(8)));
typedef unsigned short ushx8 __attribute__((ext_vector_type(8)));
typedef float f32x4 __attribute__((ext_vector_type(4)));

#define DEV static __device__ __forceinline__

DEV float bf2f(ushort_t h) {
    union { unsigned u; float f; } v;
    v.u = ((unsigned)h) << 16;
    return v.f;
}
DEV ushort_t f2bf(float f) {
    union { float f; unsigned u; } v;
    v.f = f;
    unsigned r = v.u + 0x7fffu + ((v.u >> 16) & 1u);
    return (ushort_t)(r >> 16);
}
// runtime-dtype input read (flat element index): flag -> fp32, else bf16 bits
DEV float ldin(const void* p, size_t i, int isf32) {
    return isf32 ? ((const float*)p)[i] : bf2f(((const ushort_t*)p)[i]);
}
DEV bf16x8 ldfrag(const ushort_t* p) {
    return __builtin_bit_cast(bf16x8, *(const ushx8*)p);
}
// async global->LDS, 16 B per lane; LDS dest = wave-uniform base + lane*16
DEV void gld16(const ushort_t* g, ushort_t* l) {
    __builtin_amdgcn_global_load_lds((const __attribute__((address_space(1))) void*)g,
                                     (__attribute__((address_space(3))) void*)l, 16, 0, 0);
}

// ---------------- dtype detector: writes 1 if inputs are fp32 ----------------
__global__ __launch_bounds__(256) void detect_kernel(const ushort_t* __restrict__ x,
                                                     int* __restrict__ flag) {
    __shared__ int bad;
    if (threadIdx.x == 0) bad = 0;
    __syncthreads();
    int b = 0;
#pragma unroll
    for (int i = 0; i < 8; ++i) {
        float v = fabsf(bf2f(x[threadIdx.x * 8 + i]));
        if (!(v <= 16384.f)) b = 1;  // catches huge exponents AND NaN
    }
    if (b) atomicOr(&bad, 1);
    __syncthreads();
    if (threadIdx.x == 0) *flag = bad;
}

// ---------------- per-layer weight pack: W[k][n] -> WT[n][k] bf16, biases -> fp32 ----
__global__ __launch_bounds__(256) void pack_kernel(const void* __restrict__ Wq, const void* __restrict__ Wk,
                                                   const void* __restrict__ Wv, const void* __restrict__ Wo,
                                                   const void* __restrict__ W1, const void* __restrict__ W2,
                                                   const void* __restrict__ bq, const void* __restrict__ bk,
                                                   const void* __restrict__ bv, const void* __restrict__ bo,
                                                   const void* __restrict__ b1, const void* __restrict__ b2,
                                                   size_t wD, size_t wF, size_t bD, size_t bF,
                                                   ushort_t* __restrict__ WqkvT, ushort_t* __restrict__ WoT,
                                                   ushort_t* __restrict__ W1T, ushort_t* __restrict__ W2T,
                                                   float* __restrict__ biasbuf,
                                                   const int* __restrict__ flag) {
    const int isf32 = *flag;
    const int id = blockIdx.x, tid = threadIdx.x;
    if (id < 3072) {
        __shared__ ushort_t T[32][33];
        const void* src;
        size_t soff;
        int srcN, dstK, n0, k0;
        ushort_t* dst;
        if (id < 768) {          // QKV -> WqkvT[1536][512]
            int nt = id >> 4, kt = id & 15;
            int qkv = nt >> 4;
            src = qkv == 0 ? Wq : (qkv == 1 ? Wk : Wv);
            soff = wD; srcN = 512; dstK = 512;
            dst = WqkvT + (size_t)(qkv * 512) * 512;
            n0 = (nt & 15) * 32; k0 = kt * 32;
        } else if (id < 1024) {  // Wo -> WoT[512][512]
            int t = id - 768; int nt = t >> 4, kt = t & 15;
            src = Wo; soff = wD; srcN = 512; dst = WoT; dstK = 512;
            n0 = nt * 32; k0 = kt * 32;
        } else if (id < 2048) {  // W1[512][2048] -> W1T[2048][512]
            int t = id - 1024; int nt = t >> 4, kt = t & 15;
            src = W1; soff = wF; srcN = 2048; dst = W1T; dstK = 512;
            n0 = nt * 32; k0 = kt * 32;
        } else {                 // W2[2048][512] -> W2T[512][2048]
            int t = id - 2048; int nt = t >> 6, kt = t & 63;
            src = W2; soff = wF; srcN = 512; dst = W2T; dstK = 2048;
            n0 = nt * 32; k0 = kt * 32;
        }
        const int col = tid & 31, rw = tid >> 5;
#pragma unroll
        for (int p = 0; p < 4; ++p) {
            int kk = rw + p * 8;
            T[kk][col] = f2bf(ldin(src, soff + (size_t)(k0 + kk) * srcN + n0 + col, isf32));
        }
        __syncthreads();
#pragma unroll
        for (int p = 0; p < 4; ++p) {
            int nn = rw + p * 8;
            dst[(size_t)(n0 + nn) * dstK + k0 + col] = T[col][nn];
        }
    } else {
        int j = (id - 3072) * 256 + tid;  // 0..4607: [bq|bk|bv|bo|b1|b2]
        float v;
        if (j < 512) v = ldin(bq, bD + j, isf32);
        else if (j < 1024) v = ldin(bk, bD + j - 512, isf32);
        else if (j < 1536) v = ldin(bv, bD + j - 1024, isf32);
        else if (j < 2048) v = ldin(bo, bD + j - 1536, isf32);
        else if (j < 4096) v = ldin(b1, bF + j - 2048, isf32);
        else v = ldin(b2, bD + j - 4096, isf32);
        biasbuf[j] = v;
    }
}

// ---------------- PE add: X(bf16) = x + pos_encoding ----------------
__global__ __launch_bounds__(256) void pe_kernel(const void* __restrict__ x,
                                                 ushort_t* __restrict__ X,
                                                 const int* __restrict__ flag) {
    const int isf32 = *flag;
    int i = blockIdx.x * 256 + threadIdx.x;
    int d = i & 511;
    int s = (i >> 9) & 1023;
    float freq = expf((float)(d & ~1) * (-9.210340371976184f / 512.f));
    float ang = (float)s * freq;
    float pe = (d & 1) ? cosf(ang) : sinf(ang);
    X[i] = f2bf(ldin(x, i, isf32) + pe);
}

// ---------------- MFMA bf16 GEMM (m97 structure, optional K-split over z) ----------
// z=0: k in [0,kSplit), bias added, writes C0. z=1: k in [kSplit,2*kSplit), no bias,
// writes C1. Launch with gridDim.z=1 and kSplit=K for the plain GEMM.
template <typename CT, bool RELU>
__global__ __launch_bounds__(256) void gemm2_kernel(const ushort_t* __restrict__ A,
                                                    const ushort_t* __restrict__ Bp,
                                                    const float* __restrict__ bias,
                                                    CT* __restrict__ C0, CT* __restrict__ C1,
                                                    int M, int K, int N, int kSplit) {
    __shared__ ushort_t As[128 * 32];
    __shared__ ushort_t Bs[128 * 32];
    const int tid = threadIdx.x;
    const int bm = blockIdx.y * 128;
    const int bn = blockIdx.x * 128;
    const int z = blockIdx.z;
    const int kBeg = z * kSplit, kEnd = kBeg + kSplit;
    CT* C = z ? C1 : C0;
    const int w = tid >> 6, lane = tid & 63;
    const int wm = (w >> 1) * 64, wn = (w & 1) * 64;

    f32x4 acc[4][4];
#pragma unroll
    for (int i = 0; i < 4; ++i)
#pragma unroll
        for (int j = 0; j < 4; ++j) acc[i][j] = (f32x4){0.f, 0.f, 0.f, 0.f};

    const int srow = tid >> 2;
    const int sko = (tid & 3) * 8;
    const ushort_t* a0 = A + (size_t)(bm + srow) * K + sko;
    const ushort_t* a1 = A + (size_t)(bm + 64 + srow) * K + sko;
    const ushort_t* b0 = Bp + (size_t)(bn + srow) * K + sko;
    const ushort_t* b1 = Bp + (size_t)(bn + 64 + srow) * K + sko;
    ushort_t* lA0 = As + tid * 8;
    ushort_t* lA1 = As + 2048 + tid * 8;
    ushort_t* lB0 = Bs + tid * 8;
    ushort_t* lB1 = Bs + 2048 + tid * 8;

    const int fm = lane & 15;
    const int fk = (lane >> 4) * 8;

    for (int k0 = kBeg; k0 < kEnd; k0 += 32) {
        gld16(a0 + k0, lA0);
        gld16(a1 + k0, lA1);
        gld16(b0 + k0, lB0);
        gld16(b1 + k0, lB1);
        __syncthreads();
        bf16x8 af[4], bfr[4];
#pragma unroll
        for (int i = 0; i < 4; ++i)
            af[i] = ldfrag(&As[(wm + i * 16 + fm) * 32 + fk]);
#pragma unroll
        for (int j = 0; j < 4; ++j)
            bfr[j] = ldfrag(&Bs[(wn + j * 16 + fm) * 32 + fk]);
#pragma unroll
        for (int i = 0; i < 4; ++i)
#pragma unroll
            for (int j = 0; j < 4; ++j)
                acc[i][j] = __builtin_amdgcn_mfma_f32_16x16x32_bf16(af[i], bfr[j], acc[i][j], 0, 0, 0);
        __syncthreads();
    }
    const int cn = lane & 15;
    const int rq = (lane >> 4) * 4;
#pragma unroll
    for (int j = 0; j < 4; ++j) {
        const int n = bn + wn + j * 16 + cn;
        const float bv = z ? 0.f : bias[n];
#pragma unroll
        for (int i = 0; i < 4; ++i) {
#pragma unroll
            for (int r = 0; r < 4; ++r) {
                const int m = bm + wm + i * 16 + rq + r;
                float v = acc[i][j][r] + bv;
                if constexpr (RELU) v = fmaxf(v, 0.f);
                if constexpr (sizeof(CT) == 4)
                    ((float*)C)[(size_t)m * N + n] = v;
                else
                    ((ushort_t*)C)[(size_t)m * N + n] = f2bf(v);
            }
        }
    }
}

// ---------------- V transpose: VT[b][h][d][s] from QKV V-part ----------------
__global__ __launch_bounds__(256) void vt_kernel(const ushort_t* __restrict__ QKV,
                                                 ushort_t* __restrict__ VT) {
    const int st = blockIdx.x, h = blockIdx.y, b = blockIdx.z;
    const int tid = threadIdx.x;
    const int s = st * 64 + (tid & 63);
    const int dc = (tid >> 6) * 16;
    const ushort_t* src = QKV + ((size_t)b * 1024 + s) * 1536 + 1024 + h * 64 + dc;
    ushx8 r0 = *(const ushx8*)src;
    ushx8 r1 = *(const ushx8*)(src + 8);
    ushort_t* dst = VT + (((size_t)(b * 8 + h)) * 64 + dc) * 1024 + s;
#pragma unroll
    for (int i = 0; i < 8; ++i) dst[(size_t)i * 1024] = r0[i];
#pragma unroll
    for (int i = 0; i < 8; ++i) dst[(size_t)(8 + i) * 1024] = r1[i];
}

// ---------------- Flash attention (MFMA, async staging, flat softmax) ----------------
__global__ __launch_bounds__(256) void fattn_kernel(const ushort_t* __restrict__ QKV,
                                                    const ushort_t* __restrict__ VT,
                                                    const int* __restrict__ lens,
                                                    ushort_t* __restrict__ O) {
    __shared__ ushort_t Qs[64 * 64];
    __shared__ ushort_t Ks[64 * 64];
    __shared__ ushort_t Vs[64 * 64];   // [d][key]
    __shared__ ushort_t Ps[64 * 72];   // padded; wave-private strips
    const int qt = blockIdx.x, h = blockIdx.y, b = blockIdx.z;
    const int tid = threadIdx.x, w = tid >> 6, L = tid & 63;
    const int len = lens[b];
    const size_t qkvb = ((size_t)b * 1024) * 1536 + (size_t)h * 64;
    const size_t vtb = ((size_t)(b * 8 + h)) * 64 * 1024;
    const int fm = L & 15, fk = (L >> 4) * 8;
    const int cl = L & 15, rq = (L >> 4) * 4;
    const int sr = tid >> 3, sc8 = (tid & 7) * 8;

    gld16(QKV + qkvb + (size_t)(qt * 64 + sr) * 1536 + sc8, Qs + tid * 8);
    gld16(QKV + qkvb + (size_t)(qt * 64 + 32 + sr) * 1536 + sc8, Qs + 2048 + tid * 8);

    float rs[4] = {0.f, 0.f, 0.f, 0.f};
    f32x4 oacc[4];
#pragma unroll
    for (int dt = 0; dt < 4; ++dt) oacc[dt] = (f32x4){0.f, 0.f, 0.f, 0.f};
    const float sscale = 0.125f * 1.44269504f;

    const int nkb = (len + 63) >> 6;
    for (int kb = 0; kb < nkb; ++kb) {
        __syncthreads();
        gld16(QKV + qkvb + 512 + (size_t)(kb * 64 + sr) * 1536 + sc8, Ks + tid * 8);
        gld16(QKV + qkvb + 512 + (size_t)(kb * 64 + 32 + sr) * 1536 + sc8, Ks + 2048 + tid * 8);
        gld16(VT + vtb + (size_t)sr * 1024 + kb * 64 + sc8, Vs + tid * 8);
        gld16(VT + vtb + (size_t)(32 + sr) * 1024 + kb * 64 + sc8, Vs + 2048 + tid * 8);
        __syncthreads();
        f32x4 sacc[4];
#pragma unroll
        for (int j = 0; j < 4; ++j) sacc[j] = (f32x4){0.f, 0.f, 0.f, 0.f};
#pragma unroll
        for (int st = 0; st < 2; ++st) {
            bf16x8 af = ldfrag(&Qs[(w * 16 + fm) * 64 + st * 32 + fk]);
#pragma unroll
            for (int j = 0; j < 4; ++j) {
                bf16x8 bf = ldfrag(&Ks[(j * 16 + fm) * 64 + st * 32 + fk]);
                sacc[j] = __builtin_amdgcn_mfma_f32_16x16x32_bf16(af, bf, sacc[j], 0, 0, 0);
            }
        }
        const int colb = kb * 64;
#pragma unroll
        for (int j = 0; j < 4; ++j) {
            const bool mk = (colb + j * 16 + cl) >= len;
#pragma unroll
            for (int r = 0; r < 4; ++r) {
                float p = mk ? 0.f : exp2f(sacc[j][r] * sscale);
                sacc[j][r] = p;
                rs[r] += p;
            }
        }
#pragma unroll
        for (int j = 0; j < 4; ++j)
#pragma unroll
            for (int r = 0; r < 4; ++r)
                Ps[(w * 16 + rq + r) * 72 + j * 16 + cl] = f2bf(sacc[j][r]);
#pragma unroll
        for (int st = 0; st < 2; ++st) {
            bf16x8 pf = ldfrag(&Ps[(w * 16 + fm) * 72 + st * 32 + fk]);
#pragma unroll
            for (int dt = 0; dt < 4; ++dt) {
                bf16x8 vf = ldfrag(&Vs[(dt * 16 + fm) * 64 + st * 32 + fk]);
                oacc[dt] = __builtin_amdgcn_mfma_f32_16x16x32_bf16(pf, vf, oacc[dt], 0, 0, 0);
            }
        }
    }
#pragma unroll
    for (int msk = 1; msk <= 8; msk <<= 1)
#pragma unroll
        for (int r = 0; r < 4; ++r) rs[r] += __shfl_xor(rs[r], msk);
    float inv[4];
#pragma unroll
    for (int r = 0; r < 4; ++r) inv[r] = 1.f / rs[r];
    const size_t ob = ((size_t)b * 1024) * 512 + (size_t)h * 64;
#pragma unroll
    for (int dt = 0; dt < 4; ++dt) {
#pragma unroll
        for (int r = 0; r < 4; ++r) {
            const int q = qt * 64 + w * 16 + rq + r;
            const int d = dt * 16 + cl;
            O[ob + (size_t)q * 512 + d] = f2bf(oacc[dt][r] * inv[r]);
        }
    }
}

// ---------------- Residual + LayerNorm (single fp32 operand) ----------------
__global__ __launch_bounds__(256) void ln_kernel(const ushort_t* __restrict__ A,
                                                 const float* __restrict__ B,
                                                 const void* __restrict__ g,
                                                 const void* __restrict__ be, size_t pOff,
                                                 ushort_t* __restrict__ out,
                                                 const int* __restrict__ flag) {
    const int isf32 = *flag;
    __shared__ float red[8];
    const int row = blockIdx.x, tid = threadIdx.x;
    const int wave = tid >> 6, lane = tid & 63;
    const size_t off = (size_t)row * 512;
    float v0 = bf2f(A[off + tid]) + B[off + tid];
    float v1 = bf2f(A[off + tid + 256]) + B[off + tid + 256];
    float s = v0 + v1;
#pragma unroll
    for (int o = 32; o; o >>= 1) s += __shfl_xor(s, o);
    if (lane == 0) red[wave] = s;
    __syncthreads();
    const float mean = (red[0] + red[1] + red[2] + red[3]) * (1.f / 512.f);
    const float d0 = v0 - mean, d1 = v1 - mean;
    float ss = d0 * d0 + d1 * d1;
#pragma unroll
    for (int o = 32; o; o >>= 1) ss += __shfl_xor(ss, o);
    if (lane == 0) red[4 + wave] = ss;
    __syncthreads();
    const float var = (red[4] + red[5] + red[6] + red[7]) * (1.f / 511.f);
    const float inv = 1.f / (sqrtf(var) + 1e-6f);
    out[off + tid] = f2bf(ldin(g, pOff + tid, isf32) * d0 * inv + ldin(be, pOff + tid, isf32));
    out[off + tid + 256] = f2bf(ldin(g, pOff + tid + 256, isf32) * d1 * inv + ldin(be, pOff + tid + 256, isf32));
}

// ---------------- Residual + LayerNorm (two fp32 operands: split-K halves) --------
__global__ __launch_bounds__(256) void ln2_kernel(const ushort_t* __restrict__ A,
                                                  const float* __restrict__ B,
                                                  const float* __restrict__ B2,
                                                  const void* __restrict__ g,
                                                  const void* __restrict__ be, size_t pOff,
                                                  ushort_t* __restrict__ out,
                                                  const int* __restrict__ flag) {
    const int isf32 = *flag;
    __shared__ float red[8];
    const int row = blockIdx.x, tid = threadIdx.x;
    const int wave = tid >> 6, lane = tid & 63;
    const size_t off = (size_t)row * 512;
    float v0 = bf2f(A[off + tid]) + B[off + tid] + B2[off + tid];
    float v1 = bf2f(A[off + tid + 256]) + B[off + tid + 256] + B2[off + tid + 256];
    float s = v0 + v1;
#pragma unroll
    for (int o = 32; o; o >>= 1) s += __shfl_xor(s, o);
    if (lane == 0) red[wave] = s;
    __syncthreads();
    const float mean = (red[0] + red[1] + red[2] + red[3]) * (1.f / 512.f);
    const float d0 = v0 - mean, d1 = v1 - mean;
    float ss = d0 * d0 + d1 * d1;
#pragma unroll
    for (int o = 32; o; o >>= 1) ss += __shfl_xor(ss, o);
    if (lane == 0) red[4 + wave] = ss;
    __syncthreads();
    const float var = (red[4] + red[5] + red[6] + red[7]) * (1.f / 511.f);
    const float inv = 1.f / (sqrtf(var) + 1e-6f);
    out[off + tid] = f2bf(ldin(g, pOff + tid, isf32) * d0 * inv + ldin(be, pOff + tid, isf32));
    out[off + tid + 256] = f2bf(ldin(g, pOff + tid + 256, isf32) * d1 * inv + ldin(be, pOff + tid + 256, isf32));
}

// ---------------- final bf16 -> output dtype ----------------
__global__ __launch_bounds__(256) void out_kernel(const ushort_t* __restrict__ X,
                                                  void* __restrict__ out,
                                                  const int* __restrict__ flag) {
    const int isf32 = *flag;
    int i = blockIdx.x * 256 + threadIdx.x;
    if (isf32)
        ((float*)out)[i] = bf2f(X[i]);
    else
        ((ushort_t*)out)[i] = X[i];
}

extern "C" void kernel_launch(void* const* d_in, const int* in_sizes, int n_in,
                              void* d_out, int out_size, void* d_ws, size_t ws_size,
                              hipStream_t stream) {
    const void* x   = d_in[0];
    const int* lens = (const int*)d_in[1];
    const void* Wq  = d_in[2];
    const void* bq  = d_in[3];
    const void* Wk  = d_in[4];
    const void* bk  = d_in[5];
    const void* Wv  = d_in[6];
    const void* bv  = d_in[7];
    const void* Wo  = d_in[8];
    const void* bo  = d_in[9];
    const void* W1  = d_in[10];
    const void* b1  = d_in[11];
    const void* W2  = d_in[12];
    const void* b2  = d_in[13];
    const void* g1  = d_in[14];
    const void* be1 = d_in[15];
    const void* g2  = d_in[16];
    const void* be2 = d_in[17];

    const size_t NE = (size_t)8 * 1024 * 512;
    char* base = (char*)d_ws;
    int*      flag    = (int*)base;                         // 256 B
    ushort_t* WqkvT   = (ushort_t*)(base + 256);            // 1.5 MB
    ushort_t* WoT     = (ushort_t*)(base + 1573120);        // 0.5 MB
    ushort_t* W1T     = (ushort_t*)(base + 2097408);        // 2 MB
    ushort_t* W2T     = (ushort_t*)(base + 4194560);        // 2 MB
    float*    biasbuf = (float*)(base + 6291712);           // 18 KB
    ushort_t* B123    = (ushort_t*)(base + 8388608);        // 24 MB  QKV (stride 1536)
    ushort_t* B4      = (ushort_t*)(base + 33554432);       // 8 MB   ATT out
    ushort_t* B0      = (ushort_t*)(base + 41943040);       // 8 MB   X / Y
    float*    R       = (float*)(base + 50331648);          // 16 MB  fp32 residual (48-64 MB)
    ushort_t* VT      = (ushort_t*)R;                       // 8 MB, dead before Wo-GEMM writes R
    ushort_t* F1      = B123;                               // 32 MB spans B123+B4
    const bool bigws  = ws_size >= (size_t)84 * 1024 * 1024;
    float*    R2      = bigws ? (float*)(base + 67108864) : R;  // 16 MB (64-80 MB)

    dim3 blk(256);
    dim3 gQKV(12, 64, 1);
    dim3 gF(16, 64, 1);
    dim3 gD1(4, 64, 1);
    dim3 gD2(4, 64, 2);

    detect_kernel<<<1, blk, 0, stream>>>((const ushort_t*)x, flag);
    pe_kernel<<<NE / 256, blk, 0, stream>>>(x, B0, flag);
    for (int l = 0; l < 4; ++l) {
        const size_t wD = (size_t)l * 512 * 512;
        const size_t wF = (size_t)l * 512 * 2048;
        const size_t bD = (size_t)l * 512;
        const size_t bF = (size_t)l * 2048;

        pack_kernel<<<3090, blk, 0, stream>>>(Wq, Wk, Wv, Wo, W1, W2,
                                              bq, bk, bv, bo, b1, b2,
                                              wD, wF, bD, bF,
                                              WqkvT, WoT, W1T, W2T, biasbuf, flag);
        gemm2_kernel<ushort_t, false><<<gQKV, blk, 0, stream>>>(B0, WqkvT, biasbuf, B123, B123, 8192, 512, 1536, 512);
        vt_kernel<<<dim3(16, 8, 8), blk, 0, stream>>>(B123, VT);
        fattn_kernel<<<dim3(16, 8, 8), blk, 0, stream>>>(B123, VT, lens, B4);
        if (bigws) {
            gemm2_kernel<float, false><<<gD2, blk, 0, stream>>>(B4, WoT, biasbuf + 1536, R, R2, 8192, 512, 512, 256);
            ln2_kernel<<<8192, blk, 0, stream>>>(B0, R, R2, g1, be1, bD, B0, flag);
            gemm2_kernel<ushort_t, true><<<gF, blk, 0, stream>>>(B0, W1T, biasbuf + 2048, F1, F1, 8192, 512, 2048, 512);
            gemm2_kernel<float, false><<<gD2, blk, 0, stream>>>(F1, W2T, biasbuf + 4096, R, R2, 8192, 2048, 512, 1024);
            ln2_kernel<<<8192, blk, 0, stream>>>(B0, R, R2, g2, be2, bD, B0, flag);
        } else {
            gemm2_kernel<float, false><<<gD1, blk, 0, stream>>>(B4, WoT, biasbuf + 1536, R, R, 8192, 512, 512, 512);
            ln_kernel<<<8192, blk, 0, stream>>>(B0, R, g1, be1, bD, B0, flag);
            gemm2_kernel<ushort_t, true><<<gF, blk, 0, stream>>>(B0, W1T, biasbuf + 2048, F1, F1, 8192, 512, 2048, 512);
            gemm2_kernel<float, false><<<gD1, blk, 0, stream>>>(F1, W2T, biasbuf + 4096, R, R, 8192, 2048, 512, 2048);
            ln_kernel<<<8192, blk, 0, stream>>>(B0, R, g2, be2, bD, B0, flag);
        }
    }
    out_kernel<<<NE / 256, blk, 0, stream>>>(B0, d_out, flag);
}

// Round 8
// 863.436 us; speedup vs baseline: 10.0457x; 1.0333x over previous
//
#include <hip/hip_runtime.h>
#include <stdint.h>
#include <math.h>

typedef unsigned short ushort_t;
typedef __bf16 bf16x8 __attribute__((ext_vector_type(8)));
typedef unsigned short ushx8 __attribute__((ext_vector_type(8)));
typedef float f32x4 __attribute__((ext_vector_type(4)));

#define DEV static __device__ __forceinline__

DEV float bf2f(ushort_t h) {
    union { unsigned u; float f; } v;
    v.u = ((unsigned)h) << 16;
    return v.f;
}
DEV ushort_t f2bf(float f) {
    union { float f; unsigned u; } v;
    v.f = f;
    unsigned r = v.u + 0x7fffu + ((v.u >> 16) & 1u);
    return (ushort_t)(r >> 16);
}
// runtime-dtype input read (flat element index): flag -> fp32, else bf16 bits
DEV float ldin(const void* p, size_t i, int isf32) {
    return isf32 ? ((const float*)p)[i] : bf2f(((const ushort_t*)p)[i]);
}
DEV bf16x8 ldfrag(const ushort_t* p) {
    return __builtin_bit_cast(bf16x8, *(const ushx8*)p);
}
// async global->LDS, 16 B per lane; LDS dest = wave-uniform base + lane*16
DEV void gld16(const ushort_t* g, ushort_t* l) {
    __builtin_amdgcn_global_load_lds((const __attribute__((address_space(1))) void*)g,
                                     (__attribute__((address_space(3))) void*)l, 16, 0, 0);
}

// ---------------- dtype detector: writes 1 if inputs are fp32 ----------------
__global__ __launch_bounds__(256) void detect_kernel(const ushort_t* __restrict__ x,
                                                     int* __restrict__ flag) {
    __shared__ int bad;
    if (threadIdx.x == 0) bad = 0;
    __syncthreads();
    int b = 0;
#pragma unroll
    for (int i = 0; i < 8; ++i) {
        float v = fabsf(bf2f(x[threadIdx.x * 8 + i]));
        if (!(v <= 16384.f)) b = 1;  // catches huge exponents AND NaN
    }
    if (b) atomicOr(&bad, 1);
    __syncthreads();
    if (threadIdx.x == 0) *flag = bad;
}

// ---------------- per-layer weight pack: W[k][n] -> WT[n][k] bf16, biases -> fp32 ----
__global__ __launch_bounds__(256) void pack_kernel(const void* __restrict__ Wq, const void* __restrict__ Wk,
                                                   const void* __restrict__ Wv, const void* __restrict__ Wo,
                                                   const void* __restrict__ W1, const void* __restrict__ W2,
                                                   const void* __restrict__ bq, const void* __restrict__ bk,
                                                   const void* __restrict__ bv, const void* __restrict__ bo,
                                                   const void* __restrict__ b1, const void* __restrict__ b2,
                                                   size_t wD, size_t wF, size_t bD, size_t bF,
                                                   ushort_t* __restrict__ WqkvT, ushort_t* __restrict__ WoT,
                                                   ushort_t* __restrict__ W1T, ushort_t* __restrict__ W2T,
                                                   float* __restrict__ biasbuf,
                                                   const int* __restrict__ flag) {
    const int isf32 = *flag;
    const int id = blockIdx.x, tid = threadIdx.x;
    if (id < 3072) {
        __shared__ ushort_t T[32][33];
        const void* src;
        size_t soff;
        int srcN, dstK, n0, k0;
        ushort_t* dst;
        if (id < 768) {          // QKV -> WqkvT[1536][512]
            int nt = id >> 4, kt = id & 15;
            int qkv = nt >> 4;
            src = qkv == 0 ? Wq : (qkv == 1 ? Wk : Wv);
            soff = wD; srcN = 512; dstK = 512;
            dst = WqkvT + (size_t)(qkv * 512) * 512;
            n0 = (nt & 15) * 32; k0 = kt * 32;
        } else if (id < 1024) {  // Wo -> WoT[512][512]
            int t = id - 768; int nt = t >> 4, kt = t & 15;
            src = Wo; soff = wD; srcN = 512; dst = WoT; dstK = 512;
            n0 = nt * 32; k0 = kt * 32;
        } else if (id < 2048) {  // W1[512][2048] -> W1T[2048][512]
            int t = id - 1024; int nt = t >> 4, kt = t & 15;
            src = W1; soff = wF; srcN = 2048; dst = W1T; dstK = 512;
            n0 = nt * 32; k0 = kt * 32;
        } else {                 // W2[2048][512] -> W2T[512][2048]
            int t = id - 2048; int nt = t >> 6, kt = t & 63;
            src = W2; soff = wF; srcN = 512; dst = W2T; dstK = 2048;
            n0 = nt * 32; k0 = kt * 32;
        }
        const int col = tid & 31, rw = tid >> 5;
#pragma unroll
        for (int p = 0; p < 4; ++p) {
            int kk = rw + p * 8;
            T[kk][col] = f2bf(ldin(src, soff + (size_t)(k0 + kk) * srcN + n0 + col, isf32));
        }
        __syncthreads();
#pragma unroll
        for (int p = 0; p < 4; ++p) {
            int nn = rw + p * 8;
            dst[(size_t)(n0 + nn) * dstK + k0 + col] = T[col][nn];
        }
    } else {
        int j = (id - 3072) * 256 + tid;  // 0..4607: [bq|bk|bv|bo|b1|b2]
        float v;
        if (j < 512) v = ldin(bq, bD + j, isf32);
        else if (j < 1024) v = ldin(bk, bD + j - 512, isf32);
        else if (j < 1536) v = ldin(bv, bD + j - 1024, isf32);
        else if (j < 2048) v = ldin(bo, bD + j - 1536, isf32);
        else if (j < 4096) v = ldin(b1, bF + j - 2048, isf32);
        else v = ldin(b2, bD + j - 4096, isf32);
        biasbuf[j] = v;
    }
}

// ---------------- PE add: X(bf16) = x + pos_encoding ----------------
__global__ __launch_bounds__(256) void pe_kernel(const void* __restrict__ x,
                                                 ushort_t* __restrict__ X,
                                                 const int* __restrict__ flag) {
    const int isf32 = *flag;
    int i = blockIdx.x * 256 + threadIdx.x;
    int d = i & 511;
    int s = (i >> 9) & 1023;
    float freq = expf((float)(d & ~1) * (-9.210340371976184f / 512.f));
    float ang = (float)s * freq;
    float pe = (d & 1) ? cosf(ang) : sinf(ang);
    X[i] = f2bf(ldin(x, i, isf32) + pe);
}

// ---------------- MFMA bf16 GEMM (m97 structure, optional K-split over z) ----------
template <typename CT, bool RELU>
__global__ __launch_bounds__(256) void gemm2_kernel(const ushort_t* __restrict__ A,
                                                    const ushort_t* __restrict__ Bp,
                                                    const float* __restrict__ bias,
                                                    CT* __restrict__ C0, CT* __restrict__ C1,
                                                    int M, int K, int N, int kSplit) {
    __shared__ ushort_t As[128 * 32];
    __shared__ ushort_t Bs[128 * 32];
    const int tid = threadIdx.x;
    const int bm = blockIdx.y * 128;
    const int bn = blockIdx.x * 128;
    const int z = blockIdx.z;
    const int kBeg = z * kSplit, kEnd = kBeg + kSplit;
    CT* C = z ? C1 : C0;
    const int w = tid >> 6, lane = tid & 63;
    const int wm = (w >> 1) * 64, wn = (w & 1) * 64;

    f32x4 acc[4][4];
#pragma unroll
    for (int i = 0; i < 4; ++i)
#pragma unroll
        for (int j = 0; j < 4; ++j) acc[i][j] = (f32x4){0.f, 0.f, 0.f, 0.f};

    const int srow = tid >> 2;
    const int sko = (tid & 3) * 8;
    const ushort_t* a0 = A + (size_t)(bm + srow) * K + sko;
    const ushort_t* a1 = A + (size_t)(bm + 64 + srow) * K + sko;
    const ushort_t* b0 = Bp + (size_t)(bn + srow) * K + sko;
    const ushort_t* b1 = Bp + (size_t)(bn + 64 + srow) * K + sko;
    ushort_t* lA0 = As + tid * 8;
    ushort_t* lA1 = As + 2048 + tid * 8;
    ushort_t* lB0 = Bs + tid * 8;
    ushort_t* lB1 = Bs + 2048 + tid * 8;

    const int fm = lane & 15;
    const int fk = (lane >> 4) * 8;

    for (int k0 = kBeg; k0 < kEnd; k0 += 32) {
        gld16(a0 + k0, lA0);
        gld16(a1 + k0, lA1);
        gld16(b0 + k0, lB0);
        gld16(b1 + k0, lB1);
        __syncthreads();
        bf16x8 af[4], bfr[4];
#pragma unroll
        for (int i = 0; i < 4; ++i)
            af[i] = ldfrag(&As[(wm + i * 16 + fm) * 32 + fk]);
#pragma unroll
        for (int j = 0; j < 4; ++j)
            bfr[j] = ldfrag(&Bs[(wn + j * 16 + fm) * 32 + fk]);
#pragma unroll
        for (int i = 0; i < 4; ++i)
#pragma unroll
            for (int j = 0; j < 4; ++j)
                acc[i][j] = __builtin_amdgcn_mfma_f32_16x16x32_bf16(af[i], bfr[j], acc[i][j], 0, 0, 0);
        __syncthreads();
    }
    const int cn = lane & 15;
    const int rq = (lane >> 4) * 4;
#pragma unroll
    for (int j = 0; j < 4; ++j) {
        const int n = bn + wn + j * 16 + cn;
        const float bv = z ? 0.f : bias[n];
#pragma unroll
        for (int i = 0; i < 4; ++i) {
#pragma unroll
            for (int r = 0; r < 4; ++r) {
                const int m = bm + wm + i * 16 + rq + r;
                float v = acc[i][j][r] + bv;
                if constexpr (RELU) v = fmaxf(v, 0.f);
                if constexpr (sizeof(CT) == 4)
                    ((float*)C)[(size_t)m * N + n] = v;
                else
                    ((ushort_t*)C)[(size_t)m * N + n] = f2bf(v);
            }
        }
    }
}

// ---------------- V transpose via LDS: VT[b][h][d][s], coalesced both ways --------
__global__ __launch_bounds__(256) void vt_kernel(const ushort_t* __restrict__ QKV,
                                                 ushort_t* __restrict__ VT) {
    __shared__ ushort_t T[64][72];
    const int st = blockIdx.x, h = blockIdx.y, b = blockIdx.z;
    const int tid = threadIdx.x;
    // read: thread = (s_local, 16-d chunk), contiguous 32 B loads
    const int s = tid & 63;
    const int dc = (tid >> 6) * 16;
    const ushort_t* src = QKV + ((size_t)b * 1024 + st * 64 + s) * 1536 + 1024 + h * 64 + dc;
    ushx8 r0 = *(const ushx8*)src;
    ushx8 r1 = *(const ushx8*)(src + 8);
#pragma unroll
    for (int i = 0; i < 8; ++i) T[dc + i][s] = r0[i];
#pragma unroll
    for (int i = 0; i < 8; ++i) T[dc + 8 + i][s] = r1[i];
    __syncthreads();
    // write: thread = (d, 16-s chunk), contiguous 32 B stores
    const int d = tid >> 2;
    const int sc = (tid & 3) * 16;
    ushort_t* dst = VT + (((size_t)(b * 8 + h)) * 64 + d) * 1024 + st * 64 + sc;
    *(ushx8*)dst = *(const ushx8*)&T[d][sc];
    *(ushx8*)(dst + 8) = *(const ushx8*)&T[d][sc + 8];
}

// ---------------- Flash attention (MFMA, async staging, XOR-swizzled LDS) ----------
// QKV rows of 1536 (Q|K|V). VT[b][h][d][s]. O row stride 512.
// LDS tiles are [64][64] ushorts; logical chunk g of row r lives at physical
// chunk g^(r&7) -- implemented by swizzling the global SOURCE address per lane
// (DMA dest stays linear), and the frag-read address. Kills the stride-128B
// 16-way bank degeneracy.
__global__ __launch_bounds__(256) void fattn_kernel(const ushort_t* __restrict__ QKV,
                                                    const ushort_t* __restrict__ VT,
                                                    const int* __restrict__ lens,
                                                    ushort_t* __restrict__ O) {
    __shared__ ushort_t Qs[64 * 64];
    __shared__ ushort_t Ks[64 * 64];
    __shared__ ushort_t Vs[64 * 64];   // [d][key]
    __shared__ ushort_t Ps[64 * 72];   // padded; wave-private strips
    const int qt = blockIdx.x, h = blockIdx.y, b = blockIdx.z;
    const int tid = threadIdx.x, w = tid >> 6, L = tid & 63;
    const int len = lens[b];
    const size_t qkvb = ((size_t)b * 1024) * 1536 + (size_t)h * 64;
    const size_t vtb = ((size_t)(b * 8 + h)) * 64 * 1024;
    const int fm = L & 15, q4 = L >> 4;
    const int cl = L & 15, rq = (L >> 4) * 4;
    const int sr = tid >> 3;                    // staging row 0..31 (and +32)
    const int gch = (tid & 7) ^ (sr & 7);       // logical chunk fetched by this lane
    const int sw = fm & 7;                      // frag-read swizzle key (row&7)

    gld16(QKV + qkvb + (size_t)(qt * 64 + sr) * 1536 + gch * 8, Qs + tid * 8);
    gld16(QKV + qkvb + (size_t)(qt * 64 + 32 + sr) * 1536 + gch * 8, Qs + 2048 + tid * 8);

    float rs[4] = {0.f, 0.f, 0.f, 0.f};
    f32x4 oacc[4];
#pragma unroll
    for (int dt = 0; dt < 4; ++dt) oacc[dt] = (f32x4){0.f, 0.f, 0.f, 0.f};
    const float sscale = 0.125f * 1.44269504f;

    const int nkb = (len + 63) >> 6;
    for (int kb = 0; kb < nkb; ++kb) {
        __syncthreads();
        gld16(QKV + qkvb + 512 + (size_t)(kb * 64 + sr) * 1536 + gch * 8, Ks + tid * 8);
        gld16(QKV + qkvb + 512 + (size_t)(kb * 64 + 32 + sr) * 1536 + gch * 8, Ks + 2048 + tid * 8);
        gld16(VT + vtb + (size_t)sr * 1024 + kb * 64 + gch * 8, Vs + tid * 8);
        gld16(VT + vtb + (size_t)(32 + sr) * 1024 + kb * 64 + gch * 8, Vs + 2048 + tid * 8);
        __syncthreads();
        f32x4 sacc[4];
#pragma unroll
        for (int j = 0; j < 4; ++j) sacc[j] = (f32x4){0.f, 0.f, 0.f, 0.f};
#pragma unroll
        for (int st = 0; st < 2; ++st) {
            const int pc = ((st * 4 + q4) ^ sw) * 8;   // physical chunk offset
            bf16x8 af = ldfrag(&Qs[(w * 16 + fm) * 64 + pc]);
#pragma unroll
            for (int j = 0; j < 4; ++j) {
                bf16x8 bf = ldfrag(&Ks[(j * 16 + fm) * 64 + pc]);
                sacc[j] = __builtin_amdgcn_mfma_f32_16x16x32_bf16(af, bf, sacc[j], 0, 0, 0);
            }
        }
        const int colb = kb * 64;
#pragma unroll
        for (int j = 0; j < 4; ++j) {
            const bool mk = (colb + j * 16 + cl) >= len;
#pragma unroll
            for (int r = 0; r < 4; ++r) {
                float p = mk ? 0.f : exp2f(sacc[j][r] * sscale);
                sacc[j][r] = p;
                rs[r] += p;
            }
        }
#pragma unroll
        for (int j = 0; j < 4; ++j)
#pragma unroll
            for (int r = 0; r < 4; ++r)
                Ps[(w * 16 + rq + r) * 72 + j * 16 + cl] = f2bf(sacc[j][r]);
#pragma unroll
        for (int st = 0; st < 2; ++st) {
            const int pc = ((st * 4 + q4) ^ sw) * 8;
            bf16x8 pf = ldfrag(&Ps[(w * 16 + fm) * 72 + st * 32 + q4 * 8]);
#pragma unroll
            for (int dt = 0; dt < 4; ++dt) {
                bf16x8 vf = ldfrag(&Vs[(dt * 16 + fm) * 64 + pc]);
                oacc[dt] = __builtin_amdgcn_mfma_f32_16x16x32_bf16(pf, vf, oacc[dt], 0, 0, 0);
            }
        }
    }
#pragma unroll
    for (int msk = 1; msk <= 8; msk <<= 1)
#pragma unroll
        for (int r = 0; r < 4; ++r) rs[r] += __shfl_xor(rs[r], msk);
    float inv[4];
#pragma unroll
    for (int r = 0; r < 4; ++r) inv[r] = 1.f / rs[r];
    const size_t ob = ((size_t)b * 1024) * 512 + (size_t)h * 64;
#pragma unroll
    for (int dt = 0; dt < 4; ++dt) {
#pragma unroll
        for (int r = 0; r < 4; ++r) {
            const int q = qt * 64 + w * 16 + rq + r;
            const int d = dt * 16 + cl;
            O[ob + (size_t)q * 512 + d] = f2bf(oacc[dt][r] * inv[r]);
        }
    }
}

// ---------------- Residual + LayerNorm (single fp32 operand) ----------------
__global__ __launch_bounds__(256) void ln_kernel(const ushort_t* __restrict__ A,
                                                 const float* __restrict__ B,
                                                 const void* __restrict__ g,
                                                 const void* __restrict__ be, size_t pOff,
                                                 ushort_t* __restrict__ out,
                                                 const int* __restrict__ flag) {
    const int isf32 = *flag;
    __shared__ float red[8];
    const int row = blockIdx.x, tid = threadIdx.x;
    const int wave = tid >> 6, lane = tid & 63;
    const size_t off = (size_t)row * 512;
    float v0 = bf2f(A[off + tid]) + B[off + tid];
    float v1 = bf2f(A[off + tid + 256]) + B[off + tid + 256];
    float s = v0 + v1;
#pragma unroll
    for (int o = 32; o; o >>= 1) s += __shfl_xor(s, o);
    if (lane == 0) red[wave] = s;
    __syncthreads();
    const float mean = (red[0] + red[1] + red[2] + red[3]) * (1.f / 512.f);
    const float d0 = v0 - mean, d1 = v1 - mean;
    float ss = d0 * d0 + d1 * d1;
#pragma unroll
    for (int o = 32; o; o >>= 1) ss += __shfl_xor(ss, o);
    if (lane == 0) red[4 + wave] = ss;
    __syncthreads();
    const float var = (red[4] + red[5] + red[6] + red[7]) * (1.f / 511.f);
    const float inv = 1.f / (sqrtf(var) + 1e-6f);
    out[off + tid] = f2bf(ldin(g, pOff + tid, isf32) * d0 * inv + ldin(be, pOff + tid, isf32));
    out[off + tid + 256] = f2bf(ldin(g, pOff + tid + 256, isf32) * d1 * inv + ldin(be, pOff + tid + 256, isf32));
}

// ---------------- Residual + LayerNorm (two fp32 operands: split-K halves) --------
__global__ __launch_bounds__(256) void ln2_kernel(const ushort_t* __restrict__ A,
                                                  const float* __restrict__ B,
                                                  const float* __restrict__ B2,
                                                  const void* __restrict__ g,
                                                  const void* __restrict__ be, size_t pOff,
                                                  ushort_t* __restrict__ out,
                                                  const int* __restrict__ flag) {
    const int isf32 = *flag;
    __shared__ float red[8];
    const int row = blockIdx.x, tid = threadIdx.x;
    const int wave = tid >> 6, lane = tid & 63;
    const size_t off = (size_t)row * 512;
    float v0 = bf2f(A[off + tid]) + B[off + tid] + B2[off + tid];
    float v1 = bf2f(A[off + tid + 256]) + B[off + tid + 256] + B2[off + tid + 256];
    float s = v0 + v1;
#pragma unroll
    for (int o = 32; o; o >>= 1) s += __shfl_xor(s, o);
    if (lane == 0) red[wave] = s;
    __syncthreads();
    const float mean = (red[0] + red[1] + red[2] + red[3]) * (1.f / 512.f);
    const float d0 = v0 - mean, d1 = v1 - mean;
    float ss = d0 * d0 + d1 * d1;
#pragma unroll
    for (int o = 32; o; o >>= 1) ss += __shfl_xor(ss, o);
    if (lane == 0) red[4 + wave] = ss;
    __syncthreads();
    const float var = (red[4] + red[5] + red[6] + red[7]) * (1.f / 511.f);
    const float inv = 1.f / (sqrtf(var) + 1e-6f);
    out[off + tid] = f2bf(ldin(g, pOff + tid, isf32) * d0 * inv + ldin(be, pOff + tid, isf32));
    out[off + tid + 256] = f2bf(ldin(g, pOff + tid + 256, isf32) * d1 * inv + ldin(be, pOff + tid + 256, isf32));
}

// ---------------- final bf16 -> output dtype ----------------
__global__ __launch_bounds__(256) void out_kernel(const ushort_t* __restrict__ X,
                                                  void* __restrict__ out,
                                                  const int* __restrict__ flag) {
    const int isf32 = *flag;
    int i = blockIdx.x * 256 + threadIdx.x;
    if (isf32)
        ((float*)out)[i] = bf2f(X[i]);
    else
        ((ushort_t*)out)[i] = X[i];
}

extern "C" void kernel_launch(void* const* d_in, const int* in_sizes, int n_in,
                              void* d_out, int out_size, void* d_ws, size_t ws_size,
                              hipStream_t stream) {
    const void* x   = d_in[0];
    const int* lens = (const int*)d_in[1];
    const void* Wq  = d_in[2];
    const void* bq  = d_in[3];
    const void* Wk  = d_in[4];
    const void* bk  = d_in[5];
    const void* Wv  = d_in[6];
    const void* bv  = d_in[7];
    const void* Wo  = d_in[8];
    const void* bo  = d_in[9];
    const void* W1  = d_in[10];
    const void* b1  = d_in[11];
    const void* W2  = d_in[12];
    const void* b2  = d_in[13];
    const void* g1  = d_in[14];
    const void* be1 = d_in[15];
    const void* g2  = d_in[16];
    const void* be2 = d_in[17];

    const size_t NE = (size_t)8 * 1024 * 512;
    char* base = (char*)d_ws;
    int*      flag    = (int*)base;                         // 256 B
    ushort_t* WqkvT   = (ushort_t*)(base + 256);            // 1.5 MB
    ushort_t* WoT     = (ushort_t*)(base + 1573120);        // 0.5 MB
    ushort_t* W1T     = (ushort_t*)(base + 2097408);        // 2 MB
    ushort_t* W2T     = (ushort_t*)(base + 4194560);        // 2 MB
    float*    biasbuf = (float*)(base + 6291712);           // 18 KB
    ushort_t* B123    = (ushort_t*)(base + 8388608);        // 24 MB  QKV (stride 1536)
    ushort_t* B4      = (ushort_t*)(base + 33554432);       // 8 MB   ATT out
    ushort_t* B0      = (ushort_t*)(base + 41943040);       // 8 MB   X / Y
    float*    R       = (float*)(base + 50331648);          // 16 MB  fp32 residual (48-64 MB)
    ushort_t* VT      = (ushort_t*)R;                       // 8 MB, dead before Wo-GEMM writes R
    ushort_t* F1      = B123;                               // 32 MB spans B123+B4
    const bool bigws  = ws_size >= (size_t)84 * 1024 * 1024;
    float*    R2      = bigws ? (float*)(base + 67108864) : R;  // 16 MB (64-80 MB)

    dim3 blk(256);
    dim3 gQKV(12, 64, 1);
    dim3 gF(16, 64, 1);
    dim3 gD1(4, 64, 1);
    dim3 gD2(4, 64, 2);

    detect_kernel<<<1, blk, 0, stream>>>((const ushort_t*)x, flag);
    pe_kernel<<<NE / 256, blk, 0, stream>>>(x, B0, flag);
    for (int l = 0; l < 4; ++l) {
        const size_t wD = (size_t)l * 512 * 512;
        const size_t wF = (size_t)l * 512 * 2048;
        const size_t bD = (size_t)l * 512;
        const size_t bF = (size_t)l * 2048;

        pack_kernel<<<3090, blk, 0, stream>>>(Wq, Wk, Wv, Wo, W1, W2,
                                              bq, bk, bv, bo, b1, b2,
                                              wD, wF, bD, bF,
                                              WqkvT, WoT, W1T, W2T, biasbuf, flag);
        gemm2_kernel<ushort_t, false><<<gQKV, blk, 0, stream>>>(B0, WqkvT, biasbuf, B123, B123, 8192, 512, 1536, 512);
        vt_kernel<<<dim3(16, 8, 8), blk, 0, stream>>>(B123, VT);
        fattn_kernel<<<dim3(16, 8, 8), blk, 0, stream>>>(B123, VT, lens, B4);
        if (bigws) {
            gemm2_kernel<float, false><<<gD2, blk, 0, stream>>>(B4, WoT, biasbuf + 1536, R, R2, 8192, 512, 512, 256);
            ln2_kernel<<<8192, blk, 0, stream>>>(B0, R, R2, g1, be1, bD, B0, flag);
            gemm2_kernel<ushort_t, true><<<gF, blk, 0, stream>>>(B0, W1T, biasbuf + 2048, F1, F1, 8192, 512, 2048, 512);
            gemm2_kernel<float, false><<<gD2, blk, 0, stream>>>(F1, W2T, biasbuf + 4096, R, R2, 8192, 2048, 512, 1024);
            ln2_kernel<<<8192, blk, 0, stream>>>(B0, R, R2, g2, be2, bD, B0, flag);
        } else {
            gemm2_kernel<float, false><<<gD1, blk, 0, stream>>>(B4, WoT, biasbuf + 1536, R, R, 8192, 512, 512, 512);
            ln_kernel<<<8192, blk, 0, stream>>>(B0, R, g1, be1, bD, B0, flag);
            gemm2_kernel<ushort_t, true><<<gF, blk, 0, stream>>>(B0, W1T, biasbuf + 2048, F1, F1, 8192, 512, 2048, 512);
            gemm2_kernel<float, false><<<gD1, blk, 0, stream>>>(F1, W2T, biasbuf + 4096, R, R, 8192, 2048, 512, 2048);
            ln_kernel<<<8192, blk, 0, stream>>>(B0, R, g2, be2, bD, B0, flag);
        }
    }
    out_kernel<<<NE / 256, blk, 0, stream>>>(B0, d_out, flag);
}

// Round 9
// 858.785 us; speedup vs baseline: 10.1002x; 1.0054x over previous
//
#include <hip/hip_runtime.h>
#include <stdint.h>
#include <math.h>

typedef unsigned short ushort_t;
typedef __bf16 bf16x8 __attribute__((ext_vector_type(8)));
typedef unsigned short ushx8 __attribute__((ext_vector_type(8)));
typedef float f32x4 __attribute__((ext_vector_type(4)));

#define DEV static __device__ __forceinline__

DEV float bf2f(ushort_t h) {
    union { unsigned u; float f; } v;
    v.u = ((unsigned)h) << 16;
    return v.f;
}
DEV ushort_t f2bf(float f) {
    union { float f; unsigned u; } v;
    v.f = f;
    unsigned r = v.u + 0x7fffu + ((v.u >> 16) & 1u);
    return (ushort_t)(r >> 16);
}
// runtime-dtype input read (flat element index): flag -> fp32, else bf16 bits
DEV float ldin(const void* p, size_t i, int isf32) {
    return isf32 ? ((const float*)p)[i] : bf2f(((const ushort_t*)p)[i]);
}
DEV bf16x8 ldfrag(const ushort_t* p) {
    return __builtin_bit_cast(bf16x8, *(const ushx8*)p);
}
// async global->LDS, 16 B per lane; LDS dest = wave-uniform base + lane*16
DEV void gld16(const ushort_t* g, ushort_t* l) {
    __builtin_amdgcn_global_load_lds((const __attribute__((address_space(1))) void*)g,
                                     (__attribute__((address_space(3))) void*)l, 16, 0, 0);
}

// ---------------- dtype detector: writes 1 if inputs are fp32 ----------------
__global__ __launch_bounds__(256) void detect_kernel(const ushort_t* __restrict__ x,
                                                     int* __restrict__ flag) {
    __shared__ int bad;
    if (threadIdx.x == 0) bad = 0;
    __syncthreads();
    int b = 0;
#pragma unroll
    for (int i = 0; i < 8; ++i) {
        float v = fabsf(bf2f(x[threadIdx.x * 8 + i]));
        if (!(v <= 16384.f)) b = 1;  // catches huge exponents AND NaN
    }
    if (b) atomicOr(&bad, 1);
    __syncthreads();
    if (threadIdx.x == 0) *flag = bad;
}

// ---------------- per-layer weight pack: W[k][n] -> WT[n][k] bf16, biases -> fp32 ----
__global__ __launch_bounds__(256) void pack_kernel(const void* __restrict__ Wq, const void* __restrict__ Wk,
                                                   const void* __restrict__ Wv, const void* __restrict__ Wo,
                                                   const void* __restrict__ W1, const void* __restrict__ W2,
                                                   const void* __restrict__ bq, const void* __restrict__ bk,
                                                   const void* __restrict__ bv, const void* __restrict__ bo,
                                                   const void* __restrict__ b1, const void* __restrict__ b2,
                                                   size_t wD, size_t wF, size_t bD, size_t bF,
                                                   ushort_t* __restrict__ WqkvT, ushort_t* __restrict__ WoT,
                                                   ushort_t* __restrict__ W1T, ushort_t* __restrict__ W2T,
                                                   float* __restrict__ biasbuf,
                                                   const int* __restrict__ flag) {
    const int isf32 = *flag;
    const int id = blockIdx.x, tid = threadIdx.x;
    if (id < 3072) {
        __shared__ ushort_t T[32][33];
        const void* src;
        size_t soff;
        int srcN, dstK, n0, k0;
        ushort_t* dst;
        if (id < 768) {          // QKV -> WqkvT[1536][512]
            int nt = id >> 4, kt = id & 15;
            int qkv = nt >> 4;
            src = qkv == 0 ? Wq : (qkv == 1 ? Wk : Wv);
            soff = wD; srcN = 512; dstK = 512;
            dst = WqkvT + (size_t)(qkv * 512) * 512;
            n0 = (nt & 15) * 32; k0 = kt * 32;
        } else if (id < 1024) {  // Wo -> WoT[512][512]
            int t = id - 768; int nt = t >> 4, kt = t & 15;
            src = Wo; soff = wD; srcN = 512; dst = WoT; dstK = 512;
            n0 = nt * 32; k0 = kt * 32;
        } else if (id < 2048) {  // W1[512][2048] -> W1T[2048][512]
            int t = id - 1024; int nt = t >> 4, kt = t & 15;
            src = W1; soff = wF; srcN = 2048; dst = W1T; dstK = 512;
            n0 = nt * 32; k0 = kt * 32;
        } else {                 // W2[2048][512] -> W2T[512][2048]
            int t = id - 2048; int nt = t >> 6, kt = t & 63;
            src = W2; soff = wF; srcN = 512; dst = W2T; dstK = 2048;
            n0 = nt * 32; k0 = kt * 32;
        }
        const int col = tid & 31, rw = tid >> 5;
#pragma unroll
        for (int p = 0; p < 4; ++p) {
            int kk = rw + p * 8;
            T[kk][col] = f2bf(ldin(src, soff + (size_t)(k0 + kk) * srcN + n0 + col, isf32));
        }
        __syncthreads();
#pragma unroll
        for (int p = 0; p < 4; ++p) {
            int nn = rw + p * 8;
            dst[(size_t)(n0 + nn) * dstK + k0 + col] = T[col][nn];
        }
    } else {
        int j = (id - 3072) * 256 + tid;  // 0..4607: [bq|bk|bv|bo|b1|b2]
        float v;
        if (j < 512) v = ldin(bq, bD + j, isf32);
        else if (j < 1024) v = ldin(bk, bD + j - 512, isf32);
        else if (j < 1536) v = ldin(bv, bD + j - 1024, isf32);
        else if (j < 2048) v = ldin(bo, bD + j - 1536, isf32);
        else if (j < 4096) v = ldin(b1, bF + j - 2048, isf32);
        else v = ldin(b2, bD + j - 4096, isf32);
        biasbuf[j] = v;
    }
}

// ---------------- PE add: X(bf16) = x + pos_encoding ----------------
__global__ __launch_bounds__(256) void pe_kernel(const void* __restrict__ x,
                                                 ushort_t* __restrict__ X,
                                                 const int* __restrict__ flag) {
    const int isf32 = *flag;
    int i = blockIdx.x * 256 + threadIdx.x;
    int d = i & 511;
    int s = (i >> 9) & 1023;
    float freq = expf((float)(d & ~1) * (-9.210340371976184f / 512.f));
    float ang = (float)s * freq;
    float pe = (d & 1) ? cosf(ang) : sinf(ang);
    X[i] = f2bf(ldin(x, i, isf32) + pe);
}

// ---------------- MFMA bf16 GEMM (m97 structure, optional K-split over z) ----------
// bf16 output: LDS-transposed epilogue -> full 128 B line stores (no partial-line
// write amplification). fp32 output: direct stores (64 B granular, clean).
template <typename CT, bool RELU>
__global__ __launch_bounds__(256) void gemm2_kernel(const ushort_t* __restrict__ A,
                                                    const ushort_t* __restrict__ Bp,
                                                    const float* __restrict__ bias,
                                                    CT* __restrict__ C0, CT* __restrict__ C1,
                                                    int M, int K, int N, int kSplit) {
    __shared__ ushort_t As[128 * 32];
    __shared__ ushort_t Bs[128 * 32];
    const int tid = threadIdx.x;
    const int bm = blockIdx.y * 128;
    const int bn = blockIdx.x * 128;
    const int z = blockIdx.z;
    const int kBeg = z * kSplit, kEnd = kBeg + kSplit;
    CT* C = z ? C1 : C0;
    const int w = tid >> 6, lane = tid & 63;
    const int wm = (w >> 1) * 64, wn = (w & 1) * 64;

    f32x4 acc[4][4];
#pragma unroll
    for (int i = 0; i < 4; ++i)
#pragma unroll
        for (int j = 0; j < 4; ++j) acc[i][j] = (f32x4){0.f, 0.f, 0.f, 0.f};

    const int srow = tid >> 2;
    const int sko = (tid & 3) * 8;
    const ushort_t* a0 = A + (size_t)(bm + srow) * K + sko;
    const ushort_t* a1 = A + (size_t)(bm + 64 + srow) * K + sko;
    const ushort_t* b0 = Bp + (size_t)(bn + srow) * K + sko;
    const ushort_t* b1 = Bp + (size_t)(bn + 64 + srow) * K + sko;
    ushort_t* lA0 = As + tid * 8;
    ushort_t* lA1 = As + 2048 + tid * 8;
    ushort_t* lB0 = Bs + tid * 8;
    ushort_t* lB1 = Bs + 2048 + tid * 8;

    const int fm = lane & 15;
    const int fk = (lane >> 4) * 8;

    for (int k0 = kBeg; k0 < kEnd; k0 += 32) {
        gld16(a0 + k0, lA0);
        gld16(a1 + k0, lA1);
        gld16(b0 + k0, lB0);
        gld16(b1 + k0, lB1);
        __syncthreads();
        bf16x8 af[4], bfr[4];
#pragma unroll
        for (int i = 0; i < 4; ++i)
            af[i] = ldfrag(&As[(wm + i * 16 + fm) * 32 + fk]);
#pragma unroll
        for (int j = 0; j < 4; ++j)
            bfr[j] = ldfrag(&Bs[(wn + j * 16 + fm) * 32 + fk]);
#pragma unroll
        for (int i = 0; i < 4; ++i)
#pragma unroll
            for (int j = 0; j < 4; ++j)
                acc[i][j] = __builtin_amdgcn_mfma_f32_16x16x32_bf16(af[i], bfr[j], acc[i][j], 0, 0, 0);
        __syncthreads();
    }
    const int cn = lane & 15;
    const int rq = (lane >> 4) * 4;
    if constexpr (sizeof(CT) == 2) {
        // wave-private 64x64 transpose buffer; stride 72 -> row groups 4 apart
        // start 16 banks apart (free 2-way alias)
        __shared__ ushort_t Ep[4][64 * 72];
#pragma unroll
        for (int j = 0; j < 4; ++j) {
            const float bv = z ? 0.f : bias[bn + wn + j * 16 + cn];
#pragma unroll
            for (int i = 0; i < 4; ++i) {
#pragma unroll
                for (int r = 0; r < 4; ++r) {
                    float v = acc[i][j][r] + bv;
                    if constexpr (RELU) v = fmaxf(v, 0.f);
                    Ep[w][(i * 16 + rq + r) * 72 + j * 16 + cn] = f2bf(v);
                }
            }
        }
        // wave-private: DS pipe is in-order, no barrier needed
        const int rr = lane >> 3, cc = (lane & 7) * 8;
#pragma unroll
        for (int g = 0; g < 8; ++g) {
            const int row = g * 8 + rr;
            *(ushx8*)((ushort_t*)C + (size_t)(bm + wm + row) * N + bn + wn + cc) =
                *(const ushx8*)&Ep[w][row * 72 + cc];
        }
    } else {
#pragma unroll
        for (int j = 0; j < 4; ++j) {
            const int n = bn + wn + j * 16 + cn;
            const float bv = z ? 0.f : bias[n];
#pragma unroll
            for (int i = 0; i < 4; ++i) {
#pragma unroll
                for (int r = 0; r < 4; ++r) {
                    const int m = bm + wm + i * 16 + rq + r;
                    float v = acc[i][j][r] + bv;
                    if constexpr (RELU) v = fmaxf(v, 0.f);
                    ((float*)C)[(size_t)m * N + n] = v;
                }
            }
        }
    }
}

// ---------------- V transpose via LDS: VT[b][h][d][s], coalesced both ways --------
__global__ __launch_bounds__(256) void vt_kernel(const ushort_t* __restrict__ QKV,
                                                 ushort_t* __restrict__ VT) {
    __shared__ ushort_t T[64][72];
    const int st = blockIdx.x, h = blockIdx.y, b = blockIdx.z;
    const int tid = threadIdx.x;
    const int s = tid & 63;
    const int dc = (tid >> 6) * 16;
    const ushort_t* src = QKV + ((size_t)b * 1024 + st * 64 + s) * 1536 + 1024 + h * 64 + dc;
    ushx8 r0 = *(const ushx8*)src;
    ushx8 r1 = *(const ushx8*)(src + 8);
#pragma unroll
    for (int i = 0; i < 8; ++i) T[dc + i][s] = r0[i];
#pragma unroll
    for (int i = 0; i < 8; ++i) T[dc + 8 + i][s] = r1[i];
    __syncthreads();
    const int d = tid >> 2;
    const int sc = (tid & 3) * 16;
    ushort_t* dst = VT + (((size_t)(b * 8 + h)) * 64 + d) * 1024 + st * 64 + sc;
    *(ushx8*)dst = *(const ushx8*)&T[d][sc];
    *(ushx8*)(dst + 8) = *(const ushx8*)&T[d][sc + 8];
}

// ---------------- Flash attention (MFMA, async staging, XOR-swizzled LDS) ----------
__global__ __launch_bounds__(256) void fattn_kernel(const ushort_t* __restrict__ QKV,
                                                    const ushort_t* __restrict__ VT,
                                                    const int* __restrict__ lens,
                                                    ushort_t* __restrict__ O) {
    __shared__ ushort_t Qs[64 * 64];
    __shared__ ushort_t Ks[64 * 64];
    __shared__ ushort_t Vs[64 * 64];   // [d][key]
    __shared__ ushort_t Ps[64 * 72];   // padded; wave-private strips
    const int qt = blockIdx.x, h = blockIdx.y, b = blockIdx.z;
    const int tid = threadIdx.x, w = tid >> 6, L = tid & 63;
    const int len = lens[b];
    const size_t qkvb = ((size_t)b * 1024) * 1536 + (size_t)h * 64;
    const size_t vtb = ((size_t)(b * 8 + h)) * 64 * 1024;
    const int fm = L & 15, q4 = L >> 4;
    const int cl = L & 15, rq = (L >> 4) * 4;
    const int sr = tid >> 3;
    const int gch = (tid & 7) ^ (sr & 7);
    const int sw = fm & 7;

    gld16(QKV + qkvb + (size_t)(qt * 64 + sr) * 1536 + gch * 8, Qs + tid * 8);
    gld16(QKV + qkvb + (size_t)(qt * 64 + 32 + sr) * 1536 + gch * 8, Qs + 2048 + tid * 8);

    float rs[4] = {0.f, 0.f, 0.f, 0.f};
    f32x4 oacc[4];
#pragma unroll
    for (int dt = 0; dt < 4; ++dt) oacc[dt] = (f32x4){0.f, 0.f, 0.f, 0.f};
    const float sscale = 0.125f * 1.44269504f;

    const int nkb = (len + 63) >> 6;
    for (int kb = 0; kb < nkb; ++kb) {
        __syncthreads();
        gld16(QKV + qkvb + 512 + (size_t)(kb * 64 + sr) * 1536 + gch * 8, Ks + tid * 8);
        gld16(QKV + qkvb + 512 + (size_t)(kb * 64 + 32 + sr) * 1536 + gch * 8, Ks + 2048 + tid * 8);
        gld16(VT + vtb + (size_t)sr * 1024 + kb * 64 + gch * 8, Vs + tid * 8);
        gld16(VT + vtb + (size_t)(32 + sr) * 1024 + kb * 64 + gch * 8, Vs + 2048 + tid * 8);
        __syncthreads();
        f32x4 sacc[4];
#pragma unroll
        for (int j = 0; j < 4; ++j) sacc[j] = (f32x4){0.f, 0.f, 0.f, 0.f};
#pragma unroll
        for (int st = 0; st < 2; ++st) {
            const int pc = ((st * 4 + q4) ^ sw) * 8;
            bf16x8 af = ldfrag(&Qs[(w * 16 + fm) * 64 + pc]);
#pragma unroll
            for (int j = 0; j < 4; ++j) {
                bf16x8 bf = ldfrag(&Ks[(j * 16 + fm) * 64 + pc]);
                sacc[j] = __builtin_amdgcn_mfma_f32_16x16x32_bf16(af, bf, sacc[j], 0, 0, 0);
            }
        }
        const int colb = kb * 64;
#pragma unroll
        for (int j = 0; j < 4; ++j) {
            const bool mk = (colb + j * 16 + cl) >= len;
#pragma unroll
            for (int r = 0; r < 4; ++r) {
                float p = mk ? 0.f : exp2f(sacc[j][r] * sscale);
                sacc[j][r] = p;
                rs[r] += p;
            }
        }
#pragma unroll
        for (int j = 0; j < 4; ++j)
#pragma unroll
            for (int r = 0; r < 4; ++r)
                Ps[(w * 16 + rq + r) * 72 + j * 16 + cl] = f2bf(sacc[j][r]);
#pragma unroll
        for (int st = 0; st < 2; ++st) {
            const int pc = ((st * 4 + q4) ^ sw) * 8;
            bf16x8 pf = ldfrag(&Ps[(w * 16 + fm) * 72 + st * 32 + q4 * 8]);
#pragma unroll
            for (int dt = 0; dt < 4; ++dt) {
                bf16x8 vf = ldfrag(&Vs[(dt * 16 + fm) * 64 + pc]);
                oacc[dt] = __builtin_amdgcn_mfma_f32_16x16x32_bf16(pf, vf, oacc[dt], 0, 0, 0);
            }
        }
    }
#pragma unroll
    for (int msk = 1; msk <= 8; msk <<= 1)
#pragma unroll
        for (int r = 0; r < 4; ++r) rs[r] += __shfl_xor(rs[r], msk);
    float inv[4];
#pragma unroll
    for (int r = 0; r < 4; ++r) inv[r] = 1.f / rs[r];
    const size_t ob = ((size_t)b * 1024) * 512 + (size_t)h * 64;
#pragma unroll
    for (int dt = 0; dt < 4; ++dt) {
#pragma unroll
        for (int r = 0; r < 4; ++r) {
            const int q = qt * 64 + w * 16 + rq + r;
            const int d = dt * 16 + cl;
            O[ob + (size_t)q * 512 + d] = f2bf(oacc[dt][r] * inv[r]);
        }
    }
}

// ---------------- Residual + LayerNorm (single fp32 operand) ----------------
__global__ __launch_bounds__(256) void ln_kernel(const ushort_t* __restrict__ A,
                                                 const float* __restrict__ B,
                                                 const void* __restrict__ g,
                                                 const void* __restrict__ be, size_t pOff,
                                                 ushort_t* __restrict__ out,
                                                 const int* __restrict__ flag) {
    const int isf32 = *flag;
    __shared__ float red[8];
    const int row = blockIdx.x, tid = threadIdx.x;
    const int wave = tid >> 6, lane = tid & 63;
    const size_t off = (size_t)row * 512;
    float v0 = bf2f(A[off + tid]) + B[off + tid];
    float v1 = bf2f(A[off + tid + 256]) + B[off + tid + 256];
    float s = v0 + v1;
#pragma unroll
    for (int o = 32; o; o >>= 1) s += __shfl_xor(s, o);
    if (lane == 0) red[wave] = s;
    __syncthreads();
    const float mean = (red[0] + red[1] + red[2] + red[3]) * (1.f / 512.f);
    const float d0 = v0 - mean, d1 = v1 - mean;
    float ss = d0 * d0 + d1 * d1;
#pragma unroll
    for (int o = 32; o; o >>= 1) ss += __shfl_xor(ss, o);
    if (lane == 0) red[4 + wave] = ss;
    __syncthreads();
    const float var = (red[4] + red[5] + red[6] + red[7]) * (1.f / 511.f);
    const float inv = 1.f / (sqrtf(var) + 1e-6f);
    out[off + tid] = f2bf(ldin(g, pOff + tid, isf32) * d0 * inv + ldin(be, pOff + tid, isf32));
    out[off + tid + 256] = f2bf(ldin(g, pOff + tid + 256, isf32) * d1 * inv + ldin(be, pOff + tid + 256, isf32));
}

// ---------------- Residual + LayerNorm (two fp32 operands: split-K halves) --------
__global__ __launch_bounds__(256) void ln2_kernel(const ushort_t* __restrict__ A,
                                                  const float* __restrict__ B,
                                                  const float* __restrict__ B2,
                                                  const void* __restrict__ g,
                                                  const void* __restrict__ be, size_t pOff,
                                                  ushort_t* __restrict__ out,
                                                  const int* __restrict__ flag) {
    const int isf32 = *flag;
    __shared__ float red[8];
    const int row = blockIdx.x, tid = threadIdx.x;
    const int wave = tid >> 6, lane = tid & 63;
    const size_t off = (size_t)row * 512;
    float v0 = bf2f(A[off + tid]) + B[off + tid] + B2[off + tid];
    float v1 = bf2f(A[off + tid + 256]) + B[off + tid + 256] + B2[off + tid + 256];
    float s = v0 + v1;
#pragma unroll
    for (int o = 32; o; o >>= 1) s += __shfl_xor(s, o);
    if (lane == 0) red[wave] = s;
    __syncthreads();
    const float mean = (red[0] + red[1] + red[2] + red[3]) * (1.f / 512.f);
    const float d0 = v0 - mean, d1 = v1 - mean;
    float ss = d0 * d0 + d1 * d1;
#pragma unroll
    for (int o = 32; o; o >>= 1) ss += __shfl_xor(ss, o);
    if (lane == 0) red[4 + wave] = ss;
    __syncthreads();
    const float var = (red[4] + red[5] + red[6] + red[7]) * (1.f / 511.f);
    const float inv = 1.f / (sqrtf(var) + 1e-6f);
    out[off + tid] = f2bf(ldin(g, pOff + tid, isf32) * d0 * inv + ldin(be, pOff + tid, isf32));
    out[off + tid + 256] = f2bf(ldin(g, pOff + tid + 256, isf32) * d1 * inv + ldin(be, pOff + tid + 256, isf32));
}

// ---------------- final bf16 -> output dtype ----------------
__global__ __launch_bounds__(256) void out_kernel(const ushort_t* __restrict__ X,
                                                  void* __restrict__ out,
                                                  const int* __restrict__ flag) {
    const int isf32 = *flag;
    int i = blockIdx.x * 256 + threadIdx.x;
    if (isf32)
        ((float*)out)[i] = bf2f(X[i]);
    else
        ((ushort_t*)out)[i] = X[i];
}

extern "C" void kernel_launch(void* const* d_in, const int* in_sizes, int n_in,
                              void* d_out, int out_size, void* d_ws, size_t ws_size,
                              hipStream_t stream) {
    const void* x   = d_in[0];
    const int* lens = (const int*)d_in[1];
    const void* Wq  = d_in[2];
    const void* bq  = d_in[3];
    const void* Wk  = d_in[4];
    const void* bk  = d_in[5];
    const void* Wv  = d_in[6];
    const void* bv  = d_in[7];
    const void* Wo  = d_in[8];
    const void* bo  = d_in[9];
    const void* W1  = d_in[10];
    const void* b1  = d_in[11];
    const void* W2  = d_in[12];
    const void* b2  = d_in[13];
    const void* g1  = d_in[14];
    const void* be1 = d_in[15];
    const void* g2  = d_in[16];
    const void* be2 = d_in[17];

    const size_t NE = (size_t)8 * 1024 * 512;
    char* base = (char*)d_ws;
    int*      flag    = (int*)base;                         // 256 B
    ushort_t* WqkvT   = (ushort_t*)(base + 256);            // 1.5 MB
    ushort_t* WoT     = (ushort_t*)(base + 1573120);        // 0.5 MB
    ushort_t* W1T     = (ushort_t*)(base + 2097408);        // 2 MB
    ushort_t* W2T     = (ushort_t*)(base + 4194560);        // 2 MB
    float*    biasbuf = (float*)(base + 6291712);           // 18 KB
    ushort_t* B123    = (ushort_t*)(base + 8388608);        // 24 MB  QKV (stride 1536)
    ushort_t* B4      = (ushort_t*)(base + 33554432);       // 8 MB   ATT out
    ushort_t* B0      = (ushort_t*)(base + 41943040);       // 8 MB   X / Y
    float*    R       = (float*)(base + 50331648);          // 16 MB  fp32 residual (48-64 MB)
    ushort_t* VT      = (ushort_t*)R;                       // 8 MB, dead before Wo-GEMM writes R
    ushort_t* F1      = B123;                               // 32 MB spans B123+B4
    const bool bigws  = ws_size >= (size_t)84 * 1024 * 1024;
    float*    R2      = bigws ? (float*)(base + 67108864) : R;  // 16 MB (64-80 MB)

    dim3 blk(256);
    dim3 gQKV(12, 64, 1);
    dim3 gF(16, 64, 1);
    dim3 gD1(4, 64, 1);
    dim3 gD2(4, 64, 2);

    detect_kernel<<<1, blk, 0, stream>>>((const ushort_t*)x, flag);
    pe_kernel<<<NE / 256, blk, 0, stream>>>(x, B0, flag);
    for (int l = 0; l < 4; ++l) {
        const size_t wD = (size_t)l * 512 * 512;
        const size_t wF = (size_t)l * 512 * 2048;
        const size_t bD = (size_t)l * 512;
        const size_t bF = (size_t)l * 2048;

        pack_kernel<<<3090, blk, 0, stream>>>(Wq, Wk, Wv, Wo, W1, W2,
                                              bq, bk, bv, bo, b1, b2,
                                              wD, wF, bD, bF,
                                              WqkvT, WoT, W1T, W2T, biasbuf, flag);
        gemm2_kernel<ushort_t, false><<<gQKV, blk, 0, stream>>>(B0, WqkvT, biasbuf, B123, B123, 8192, 512, 1536, 512);
        vt_kernel<<<dim3(16, 8, 8), blk, 0, stream>>>(B123, VT);
        fattn_kernel<<<dim3(16, 8, 8), blk, 0, stream>>>(B123, VT, lens, B4);
        if (bigws) {
            gemm2_kernel<float, false><<<gD2, blk, 0, stream>>>(B4, WoT, biasbuf + 1536, R, R2, 8192, 512, 512, 256);
            ln2_kernel<<<8192, blk, 0, stream>>>(B0, R, R2, g1, be1, bD, B0, flag);
            gemm2_kernel<ushort_t, true><<<gF, blk, 0, stream>>>(B0, W1T, biasbuf + 2048, F1, F1, 8192, 512, 2048, 512);
            gemm2_kernel<float, false><<<gD2, blk, 0, stream>>>(F1, W2T, biasbuf + 4096, R, R2, 8192, 2048, 512, 1024);
            ln2_kernel<<<8192, blk, 0, stream>>>(B0, R, R2, g2, be2, bD, B0, flag);
        } else {
            gemm2_kernel<float, false><<<gD1, blk, 0, stream>>>(B4, WoT, biasbuf + 1536, R, R, 8192, 512, 512, 512);
            ln_kernel<<<8192, blk, 0, stream>>>(B0, R, g1, be1, bD, B0, flag);
            gemm2_kernel<ushort_t, true><<<gF, blk, 0, stream>>>(B0, W1T, biasbuf + 2048, F1, F1, 8192, 512, 2048, 512);
            gemm2_kernel<float, false><<<gD1, blk, 0, stream>>>(F1, W2T, biasbuf + 4096, R, R, 8192, 2048, 512, 2048);
            ln_kernel<<<8192, blk, 0, stream>>>(B0, R, g2, be2, bD, B0, flag);
        }
    }
    out_kernel<<<NE / 256, blk, 0, stream>>>(B0, d_out, flag);
}